// Round 11
// baseline (1196.849 us; speedup 1.0000x reference)
//
#include <hip/hip_runtime.h>

#define EPS 1e-3f

typedef __attribute__((ext_vector_type(8))) short bf16x8;
typedef __attribute__((ext_vector_type(4))) float f32x4;

__device__ __forceinline__ float sigm(float x){ return 1.0f/(1.0f + __expf(-x)); }
__device__ __forceinline__ float tanhfast(float x){ return 1.0f - 2.0f/(1.0f + __expf(2.0f*x)); }

__device__ __forceinline__ unsigned short f2b(float f){
    union { float f; unsigned u; } v; v.f = f;
    unsigned r = v.u + 0x7FFFu + ((v.u >> 16) & 1u);
    return (unsigned short)(r >> 16);
}
__device__ __forceinline__ float b2f(unsigned short h){
    union { unsigned u; float f; } v; v.u = ((unsigned)h) << 16; return v.f;
}

// ---------------- prep: x fp32 [512,256,78] -> bf16 zero-padded [512,264,96] ----------------
__global__ void __launch_bounds__(256)
prep_x(const float* __restrict__ x, unsigned short* __restrict__ xbf)
{
    const int b = blockIdx.x;
    const float* xs = x + (size_t)b*256*78;
    unsigned short* xd = xbf + (size_t)b*264*96;
    for (int p = threadIdx.x; p < 264*48; p += 256){
        int row = p / 48;
        int cp  = (p - row*48) * 2;
        int t   = row - 4;
        unsigned short v0 = 0, v1 = 0;
        if (t >= 0 && t < 256){
            if (cp   < 78) v0 = f2b(xs[t*78 + cp]);
            if (cp+1 < 78) v1 = f2b(xs[t*78 + cp + 1]);
        }
        *(unsigned int*)(xd + row*96 + cp) = (unsigned)v0 | ((unsigned)v1 << 16);
    }
}

// ---------------- prep: unified conv weights -> bf16 B-fragment layout [27][12][512] ----------------
__global__ void __launch_bounds__(256)
prep_w(const float* __restrict__ w5, const float* __restrict__ w7, const float* __restrict__ w9,
       unsigned short* __restrict__ wfrag)
{
    int g = blockIdx.x*256 + threadIdx.x;
    if (g >= 27*12*64) return;
    union { unsigned short s[8]; uint4 v; } u;
    int base = g * 8;
    #pragma unroll
    for (int e = 0; e < 8; ++e){
        int lin  = base + e;
        int slot = lin & 511;
        int fi   = lin >> 9;
        int nt   = fi % 12, kcs = fi / 12;
        int k    = kcs / 3, cs = kcs - k*3;
        int l15  = slot >> 5, r = slot & 31;
        int lg   = r >> 3, ee = r & 7;
        int ci   = cs*32 + lg*8 + ee;
        int co   = nt*16 + l15;
        float val = 0.f;
        if (ci < 78){
            if (co < 64){
                int kk = k - 2;
                if (kk >= 0 && kk < 5) val = w5[(kk*78 + ci)*64 + co];
            } else if (co < 128){
                int kk = k - 1;
                if (kk >= 0 && kk < 7) val = w7[(kk*78 + ci)*64 + (co - 64)];
            } else {
                val = w9[(k*78 + ci)*64 + (co - 128)];
            }
        }
        u.s[e] = f2b(val);
    }
    *(uint4*)(wfrag + base) = u.v;
}

// ---------------- prep: generic W[K,N] fp32 -> bf16 B-fragment layout [K/32][N/16][64][8] ----------------
__global__ void __launch_bounds__(256)
prep_wb(const float* __restrict__ W, unsigned short* __restrict__ dst, int K, int N)
{
    int idx = blockIdx.x*256 + threadIdx.x;
    int NT = N >> 4;
    int total = (K >> 5) * NT * 64;
    if (idx >= total) return;
    int l   = idx & 63;
    int rem = idx >> 6;
    int ntg = rem % NT;
    int ks  = rem / NT;
    union { unsigned short s[8]; uint4 v; } u;
    #pragma unroll
    for (int e = 0; e < 8; ++e)
        u.s[e] = f2b(W[(size_t)(ks*32 + (l>>4)*8 + e)*N + ntg*16 + (l&15)]);
    *(uint4*)(dst + (size_t)idx*8) = u.v;
}

// ---------------- prep: fold conv bias + BN ----------------
__global__ void prep_ss(const float* b5, const float* b7, const float* b9,
                        const float* g5, const float* be5, const float* m5, const float* v5,
                        const float* g7, const float* be7, const float* m7, const float* v7,
                        const float* g9, const float* be9, const float* m9, const float* v9,
                        float* __restrict__ biascat, float* __restrict__ scale, float* __restrict__ shift)
{
    int c = threadIdx.x;
    if (c >= 192) return;
    float bv, g, be, m, v;
    if (c < 64){        bv=b5[c];      g=g5[c];      be=be5[c];      m=m5[c];      v=v5[c]; }
    else if (c < 128){  int i=c-64;  bv=b7[i]; g=g7[i]; be=be7[i]; m=m7[i]; v=v7[i]; }
    else {              int i=c-128; bv=b9[i]; g=g9[i]; be=be9[i]; m=m9[i]; v=v9[i]; }
    float s = g * rsqrtf(v + EPS);
    biascat[c] = bv;
    scale[c]   = s;
    shift[c]   = be - m*s;
}

// ---------------- fused 3-conv MFMA GEMM + relu + BN + maxpool2 -> concat [512,128,192] ----------------
__global__ void __launch_bounds__(256)
conv_mfma(const unsigned short* __restrict__ xbf,
          const unsigned short* __restrict__ wfrag,
          const float* __restrict__ biascat, const float* __restrict__ scale,
          const float* __restrict__ shift,
          float* __restrict__ out)
{
    const int b = blockIdx.x, tile = blockIdx.y;
    const int tid = threadIdx.x, lane = tid & 63, wv = tid >> 6;
    const int l15 = lane & 15, lg = lane >> 4;
    const int nt0 = wv * 3;
    const int t0  = tile * 64;

    f32x4 acc[4][3];
    #pragma unroll
    for (int nt = 0; nt < 3; ++nt){
        float bv = biascat[(nt0 + nt)*16 + l15];
        #pragma unroll
        for (int mt = 0; mt < 4; ++mt)
            acc[mt][nt] = (f32x4){bv, bv, bv, bv};
    }

    const unsigned short* xb = xbf + ((size_t)b*264 + t0 + l15)*96 + lg*8;
    const unsigned short* wb = wfrag + (size_t)nt0*512 + l15*32 + lg*8;

    for (int k = 0; k < 9; ++k){
        #pragma unroll
        for (int cs = 0; cs < 3; ++cs){
            bf16x8 A[4], Bf[3];
            #pragma unroll
            for (int mt = 0; mt < 4; ++mt)
                A[mt] = *(const bf16x8*)(xb + (size_t)(k + mt*16)*96 + cs*32);
            #pragma unroll
            for (int nt = 0; nt < 3; ++nt)
                Bf[nt] = *(const bf16x8*)(wb + (size_t)((k*3 + cs)*12 + nt)*512);
            #pragma unroll
            for (int mt = 0; mt < 4; ++mt)
                #pragma unroll
                for (int nt = 0; nt < 3; ++nt)
                    acc[mt][nt] = __builtin_amdgcn_mfma_f32_16x16x32_bf16(A[mt], Bf[nt], acc[mt][nt], 0, 0, 0);
        }
    }

    #pragma unroll
    for (int nt = 0; nt < 3; ++nt){
        int col = (nt0 + nt)*16 + l15;
        float s = scale[col], sh = shift[col];
        #pragma unroll
        for (int mt = 0; mt < 4; ++mt){
            float v0 = fmaxf(acc[mt][nt][0], 0.f)*s + sh;
            float v1 = fmaxf(acc[mt][nt][1], 0.f)*s + sh;
            float v2 = fmaxf(acc[mt][nt][2], 0.f)*s + sh;
            float v3 = fmaxf(acc[mt][nt][3], 0.f)*s + sh;
            int tb = tile*32 + mt*8 + lg*2;
            out[((size_t)b*128 + tb    )*192 + col] = fmaxf(v0, v1);
            out[((size_t)b*128 + tb + 1)*192 + col] = fmaxf(v2, v3);
        }
    }
}

// ---------------- SE: compute e[512][128] only ----------------
__global__ void __launch_bounds__(128)
se_mean(const unsigned short* __restrict__ fb,
        const float* __restrict__ w1, const float* __restrict__ b1,
        const float* __restrict__ w2, const float* __restrict__ b2,
        float* __restrict__ e)
{
    int b = blockIdx.x, c = threadIdx.x;
    __shared__ float sv[128];
    __shared__ float rv[8];
    const unsigned short* fp = fb + (size_t)b*128*128 + c;
    float acc = 0.f;
    for (int t = 0; t < 128; ++t) acc += b2f(fp[t*128]);
    sv[c] = acc * (1.f/128.f);
    __syncthreads();
    if (c < 8){
        float r = b1[c];
        for (int i = 0; i < 128; ++i) r = fmaf(sv[i], w1[i*8 + c], r);
        rv[c] = fmaxf(r, 0.f);
    }
    __syncthreads();
    float ev = b2[c];
    #pragma unroll
    for (int j = 0; j < 8; ++j) ev = fmaf(rv[j], w2[j*128 + c], ev);
    e[(size_t)b*128 + c] = sigm(ev);
}

// ---------------- xp_gemm2: A[M,K] @ Wsel[K,N] + bias, bf16 out; B prepped frag layout, A dbuf ----------------
// sel = blockIdx.y / yper picks (W,bias,out,om). om: 0=[M,N], 1=V-head-transpose, 2=gate-interleave.
template<int K, bool ABF16, bool ESCALE>
__global__ void __launch_bounds__(256)
xp_gemm2(const void* __restrict__ Av,
         const unsigned short* __restrict__ W0, const unsigned short* __restrict__ W1, const unsigned short* __restrict__ W2,
         const float* __restrict__ b0p, const float* __restrict__ b1p, const float* __restrict__ b2p,
         unsigned short* __restrict__ o0, unsigned short* __restrict__ o1, unsigned short* __restrict__ o2,
         const float* __restrict__ esc,
         int N, int yper, int om0, int om1, int om2)
{
    constexpr int KS = K/32;
    __shared__ unsigned short Asm[2][128][40];
    __shared__ float esm[ESCALE ? K : 1];

    const int tid = threadIdx.x, lane = tid & 63, wv = tid >> 6;
    const int wm = wv & 1, wn = wv >> 1;
    const size_t m0 = (size_t)blockIdx.x * 128;
    const int sel = blockIdx.y / yper;
    const int n0  = (blockIdx.y - sel*yper) * 128;
    const unsigned short* W = (sel == 0) ? W0 : (sel == 1 ? W1 : W2);
    const float* bias       = (sel == 0) ? b0p : (sel == 1 ? b1p : b2p);
    unsigned short* outp    = (sel == 0) ? o0 : (sel == 1 ? o1 : o2);
    const int om            = (sel == 0) ? om0 : (sel == 1 ? om1 : om2);
    const int NTf = N >> 4;

    if constexpr (ESCALE){
        for (int i = tid; i < K; i += 256) esm[i] = esc[(size_t)blockIdx.x*K + i];
        __syncthreads();
    }

    auto stage = [&](int bq, int ksl){
        const int k0 = ksl*32;
        if constexpr (!ABF16){
            const float* Ag = (const float*)Av;
            #pragma unroll
            for (int i = 0; i < 2; ++i){
                int g = tid + i*256;
                int r = g >> 2, c8 = g & 3;
                float4 d0 = *(const float4*)(Ag + (m0 + r)*K + k0 + c8*8);
                float4 d1 = *(const float4*)(Ag + (m0 + r)*K + k0 + c8*8 + 4);
                union { unsigned short s[8]; uint4 v; } u;
                u.s[0]=f2b(d0.x); u.s[1]=f2b(d0.y); u.s[2]=f2b(d0.z); u.s[3]=f2b(d0.w);
                u.s[4]=f2b(d1.x); u.s[5]=f2b(d1.y); u.s[6]=f2b(d1.z); u.s[7]=f2b(d1.w);
                *(uint4*)&Asm[bq][r][c8*8] = u.v;
            }
        } else {
            const unsigned short* Ag = (const unsigned short*)Av;
            #pragma unroll
            for (int i = 0; i < 2; ++i){
                int g = tid + i*256;
                int r = g >> 2, c8 = g & 3;
                uint4 d = *(const uint4*)(Ag + (m0 + r)*K + k0 + c8*8);
                if constexpr (ESCALE){
                    unsigned short* s = (unsigned short*)&d;
                    #pragma unroll
                    for (int j = 0; j < 8; ++j)
                        s[j] = f2b(b2f(s[j]) * esm[k0 + c8*8 + j]);
                }
                *(uint4*)&Asm[bq][r][c8*8] = d;
            }
        }
    };

    f32x4 acc[4][4];
    #pragma unroll
    for (int nt = 0; nt < 4; ++nt){
        float bv = bias[n0 + wn*64 + nt*16 + (lane & 15)];
        #pragma unroll
        for (int mt = 0; mt < 4; ++mt)
            acc[mt][nt] = (f32x4){bv, bv, bv, bv};
    }

    stage(0, 0);
    __syncthreads();

    int buf = 0;
    for (int ks = 0; ks < KS; ++ks){
        if (ks + 1 < KS) stage(buf ^ 1, ks + 1);

        bf16x8 af[4], bfr[4];
        #pragma unroll
        for (int mt = 0; mt < 4; ++mt)
            af[mt] = *(const bf16x8*)&Asm[buf][wm*64 + mt*16 + (lane & 15)][(lane >> 4)*8];
        #pragma unroll
        for (int nt = 0; nt < 4; ++nt){
            int ntg = (n0 >> 4) + wn*4 + nt;
            bfr[nt] = *(const bf16x8*)(W + ((size_t)(ks*NTf + ntg)*64 + lane)*8);
        }
        #pragma unroll
        for (int mt = 0; mt < 4; ++mt)
            #pragma unroll
            for (int nt = 0; nt < 4; ++nt)
                acc[mt][nt] = __builtin_amdgcn_mfma_f32_16x16x32_bf16(af[mt], bfr[nt], acc[mt][nt], 0, 0, 0);
        __syncthreads();
        buf ^= 1;
    }

    const int Uq = N >> 2;
    #pragma unroll
    for (int mt = 0; mt < 4; ++mt)
        #pragma unroll
        for (int nt = 0; nt < 4; ++nt)
            #pragma unroll
            for (int r = 0; r < 4; ++r){
                size_t row = m0 + wm*64 + mt*16 + (lane >> 4)*4 + r;
                int    col = n0 + wn*64 + nt*16 + (lane & 15);
                unsigned short val = f2b(acc[mt][nt][r]);
                if (om == 0){
                    outp[row*N + col] = val;
                } else if (om == 1){
                    size_t off = ((size_t)((row >> 7)*8 + (col >> 5))*32 + (col & 31))*128 + (row & 127);
                    outp[off] = val;
                } else {
                    outp[row*N + (col & (Uq-1))*4 + (col / Uq)] = val;
                }
            }
}

// ---------------- LSTM recurrence v6: dual-direction block (fwd+bwd waves share barrier) ----------------
// Per dir: WPD=U/16 waves; wave wvl owns units wvl*16+l15, all 4 gates; lane does 4 rows' gate math.
// c in regs; h double-buffered in LDS per dir; 1 barrier/step syncs both independent recurrences.
template<int U>
__global__ void __launch_bounds__(8*U)
lstm_rec6(const unsigned short* __restrict__ xpf, const unsigned short* __restrict__ xpb,
          const float* __restrict__ Rf, const float* __restrict__ Rb,
          const float* __restrict__ bng, const float* __restrict__ bnb,
          const float* __restrict__ bnm, const float* __restrict__ bnv,
          unsigned short* __restrict__ outv)
{
    constexpr int Z   = 4*U;
    constexpr int KT  = U/32;
    constexpr int HP  = U + 8;
    constexpr int WPD = U/16;

    __shared__ unsigned short h_lds[2][2][16][HP];   // [dir][buf][row][unit]

    const int tid = threadIdx.x, lane = tid & 63, wv = tid >> 6;
    const int l15 = lane & 15, lg = lane >> 4;
    const int dir = wv / WPD;
    const int wvl = wv - dir*WPD;
    const int b0  = blockIdx.x * 16;

    const unsigned short* xp = dir ? xpb : xpf;
    const float* Rg = dir ? Rb : Rf;

    for (int i = tid; i < 2*2*16*HP; i += 8*U) ((unsigned short*)h_lds)[i] = 0;

    bf16x8 rf[KT][4];
    #pragma unroll
    for (int kt = 0; kt < KT; ++kt)
        #pragma unroll
        for (int g = 0; g < 4; ++g){
            union { unsigned short s[8]; bf16x8 v; } u;
            #pragma unroll
            for (int e = 0; e < 8; ++e)
                u.s[e] = f2b(Rg[(size_t)(kt*32 + lg*8 + e)*Z + g*U + wvl*16 + l15]);
            rf[kt][g] = u.v;
        }

    const int u_ = wvl*16 + l15;
    const int ch = dir*U + u_;
    const float bns  = bng[ch] * rsqrtf(bnv[ch] + EPS);
    const float bnsh = bnb[ch] - bnm[ch]*bns;
    float cst[4] = {0.f, 0.f, 0.f, 0.f};
    const unsigned short* xbase = xp + ((size_t)(b0 + lg*4)*128)*Z + u_*4;

    ushort4 xq[4];
    {
        const int tf = dir ? 127 : 0;
        #pragma unroll
        for (int r = 0; r < 4; ++r)
            xq[r] = *(const ushort4*)(xbase + ((size_t)r*128 + tf)*Z);
    }
    __syncthreads();

    int buf = 0;
    for (int ts = 0; ts < 128; ++ts){
        const int t = dir ? 127 - ts : ts;
        ushort4 xn[4] = {};
        if (ts < 127){
            const int tn = dir ? t - 1 : t + 1;
            #pragma unroll
            for (int r = 0; r < 4; ++r)
                xn[r] = *(const ushort4*)(xbase + ((size_t)r*128 + tn)*Z);
        }
        bf16x8 af[KT];
        #pragma unroll
        for (int kt = 0; kt < KT; ++kt)
            af[kt] = *(const bf16x8*)&h_lds[dir][buf][l15][kt*32 + lg*8];
        f32x4 acc[4];
        #pragma unroll
        for (int g = 0; g < 4; ++g) acc[g] = (f32x4){0.f,0.f,0.f,0.f};
        #pragma unroll
        for (int kt = 0; kt < KT; ++kt)
            #pragma unroll
            for (int g = 0; g < 4; ++g)
                acc[g] = __builtin_amdgcn_mfma_f32_16x16x32_bf16(af[kt], rf[kt][g], acc[g], 0, 0, 0);
        #pragma unroll
        for (int r = 0; r < 4; ++r){
            float zi = acc[0][r] + b2f(xq[r].x);
            float zf = acc[1][r] + b2f(xq[r].y);
            float zg = acc[2][r] + b2f(xq[r].z);
            float zo = acc[3][r] + b2f(xq[r].w);
            float c  = sigm(zf)*cst[r] + sigm(zi)*tanhfast(zg);
            cst[r] = c;
            float h = sigm(zo)*tanhfast(c);
            h_lds[dir][buf^1][lg*4 + r][u_] = f2b(h);
            size_t oidx = ((size_t)(b0 + lg*4 + r)*128 + t)*(size_t)(2*U) + ch;
            outv[oidx] = f2b(fmaf(h, bns, bnsh));
        }
        __syncthreads();
        buf ^= 1;
        #pragma unroll
        for (int r = 0; r < 4; ++r) xq[r] = xn[r];
    }
}

// ---------------- MFMA attention per (b, head) ----------------
__global__ void __launch_bounds__(256)
attn_kernel(const unsigned short* __restrict__ qb,
            const unsigned short* __restrict__ kb,
            const unsigned short* __restrict__ vb,
            float* __restrict__ msum)
{
    __shared__ unsigned short p_lds[128][136];
    __shared__ float red[4][2][16];

    const int b  = blockIdx.x, hd = blockIdx.y;
    const int tid = threadIdx.x, lane = tid & 63, wv = tid >> 6;
    const int m0 = wv * 32;
    const int l15 = lane & 15, lg = lane >> 4;

    bf16x8 aq[2];
    #pragma unroll
    for (int mt = 0; mt < 2; ++mt)
        aq[mt] = *(const bf16x8*)(qb + ((size_t)(b*128 + m0 + mt*16 + l15))*256 + hd*32 + lg*8);

    bf16x8 bk[8];
    #pragma unroll
    for (int nt = 0; nt < 8; ++nt)
        bk[nt] = *(const bf16x8*)(kb + ((size_t)(b*128 + nt*16 + l15))*256 + hd*32 + lg*8);

    f32x4 s[2][8];
    #pragma unroll
    for (int mt = 0; mt < 2; ++mt)
        #pragma unroll
        for (int nt = 0; nt < 8; ++nt) s[mt][nt] = (f32x4){0.f,0.f,0.f,0.f};
    #pragma unroll
    for (int mt = 0; mt < 2; ++mt)
        #pragma unroll
        for (int nt = 0; nt < 8; ++nt)
            s[mt][nt] = __builtin_amdgcn_mfma_f32_16x16x32_bf16(aq[mt], bk[nt], s[mt][nt], 0, 0, 0);

    const float scale = 0.17677669529663687f;
    #pragma unroll
    for (int mt = 0; mt < 2; ++mt)
        #pragma unroll
        for (int r = 0; r < 4; ++r){
            float mx = -1e30f;
            #pragma unroll
            for (int nt = 0; nt < 8; ++nt) mx = fmaxf(mx, s[mt][nt][r]);
            #pragma unroll
            for (int msk = 1; msk < 16; msk <<= 1) mx = fmaxf(mx, __shfl_xor(mx, msk, 64));
            float pv[8], sum = 0.f;
            #pragma unroll
            for (int nt = 0; nt < 8; ++nt){
                pv[nt] = __expf((s[mt][nt][r] - mx) * scale);
                sum += pv[nt];
            }
            #pragma unroll
            for (int msk = 1; msk < 16; msk <<= 1) sum += __shfl_xor(sum, msk, 64);
            float inv = 1.f / sum;
            int row = m0 + mt*16 + lg*4 + r;
            #pragma unroll
            for (int nt = 0; nt < 8; ++nt)
                p_lds[row][nt*16 + l15] = f2b(pv[nt] * inv);
        }
    __syncthreads();

    f32x4 o[2][2];
    #pragma unroll
    for (int mt = 0; mt < 2; ++mt)
        #pragma unroll
        for (int dn = 0; dn < 2; ++dn) o[mt][dn] = (f32x4){0.f,0.f,0.f,0.f};
    bf16x8 bv[4][2];
    #pragma unroll
    for (int kt = 0; kt < 4; ++kt)
        #pragma unroll
        for (int dn = 0; dn < 2; ++dn)
            bv[kt][dn] = *(const bf16x8*)(vb + ((size_t)(b*8 + hd)*32 + dn*16 + l15)*128 + kt*32 + lg*8);
    #pragma unroll
    for (int mt = 0; mt < 2; ++mt)
        #pragma unroll
        for (int kt = 0; kt < 4; ++kt){
            bf16x8 ap = *(const bf16x8*)&p_lds[m0 + mt*16 + l15][kt*32 + lg*8];
            #pragma unroll
            for (int dn = 0; dn < 2; ++dn)
                o[mt][dn] = __builtin_amdgcn_mfma_f32_16x16x32_bf16(ap, bv[kt][dn], o[mt][dn], 0, 0, 0);
        }

    float sm[2];
    #pragma unroll
    for (int dn = 0; dn < 2; ++dn){
        float a = 0.f;
        #pragma unroll
        for (int mt = 0; mt < 2; ++mt)
            #pragma unroll
            for (int r = 0; r < 4; ++r) a += o[mt][dn][r];
        a += __shfl_xor(a, 16, 64);
        a += __shfl_xor(a, 32, 64);
        sm[dn] = a;
    }
    if (lg == 0){
        red[wv][0][l15] = sm[0];
        red[wv][1][l15] = sm[1];
    }
    __syncthreads();
    if (tid < 32){
        int dn = tid >> 4, n = tid & 15;
        float tot = red[0][dn][n] + red[1][dn][n] + red[2][dn][n] + red[3][dn][n];
        msum[(size_t)b*256 + hd*32 + dn*16 + n] = tot * (1.f/128.f);
    }
}

// ---------------- head ----------------
__global__ void __launch_bounds__(256)
head_kernel(const float* __restrict__ msum,
            const float* __restrict__ wo, const float* __restrict__ bo,
            const float* __restrict__ d1w, const float* __restrict__ d1b,
            const float* __restrict__ g1, const float* __restrict__ b1,
            const float* __restrict__ m1, const float* __restrict__ v1,
            const float* __restrict__ d2w, const float* __restrict__ d2b,
            const float* __restrict__ g2, const float* __restrict__ b2,
            const float* __restrict__ m2, const float* __restrict__ v2,
            const float* __restrict__ d3w, const float* __restrict__ d3b,
            float* __restrict__ outp)
{
    int b = blockIdx.x, j = threadIdx.x;
    __shared__ float s1[256];
    __shared__ float s2[256];
    const float* mr = msum + (size_t)b*256;
    float acc = bo[j];
    #pragma unroll 4
    for (int i = 0; i < 256; ++i) acc = fmaf(mr[i], wo[i*256 + j], acc);
    s1[j] = acc;
    __syncthreads();
    float a1 = d1b[j];
    #pragma unroll 4
    for (int i = 0; i < 256; ++i) a1 = fmaf(s1[i], d1w[i*256 + j], a1);
    a1 = fmaxf(a1, 0.f);
    float sc1 = g1[j] * rsqrtf(v1[j] + EPS);
    a1 = a1 * sc1 + (b1[j] - m1[j] * sc1);
    s2[j] = a1;
    __syncthreads();
    if (j < 128){
        float a2 = d2b[j];
        #pragma unroll 4
        for (int i = 0; i < 256; ++i) a2 = fmaf(s2[i], d2w[i*128 + j], a2);
        a2 = fmaxf(a2, 0.f);
        float sc2 = g2[j] * rsqrtf(v2[j] + EPS);
        a2 = a2 * sc2 + (b2[j] - m2[j] * sc2);
        s1[j] = a2;
    }
    __syncthreads();
    if (j == 0){
        float a3 = d3b[0];
        for (int i = 0; i < 128; ++i) a3 = fmaf(s1[i], d3w[i], a3);
        outp[b] = sigm(a3);
    }
}

extern "C" void kernel_launch(void* const* d_in, const int* in_sizes, int n_in,
                              void* d_out, int out_size, void* d_ws, size_t ws_size,
                              hipStream_t stream)
{
    #define F(i) ((const float*)d_in[i])
    const float* x       = F(0);
    const float* conv5_w = F(1);
    const float* conv7_w = F(2);
    const float* conv9_w = F(3);
    const float* fuse_w  = F(4);
    const float* se_w1   = F(5);
    const float* se_w2   = F(6);
    const float* l1f_k   = F(7);
    const float* l1f_r   = F(8);
    const float* l1b_k   = F(9);
    const float* l1b_r   = F(10);
    const float* l2f_k   = F(11);
    const float* l2f_r   = F(12);
    const float* l2b_k   = F(13);
    const float* l2b_r   = F(14);
    const float* wq      = F(15);
    const float* wk      = F(16);
    const float* wv      = F(17);
    const float* wo      = F(18);
    const float* d1_w    = F(19);
    const float* d2_w    = F(20);
    const float* d3_w    = F(21);
    const float* conv5_b = F(22);
    const float* conv7_b = F(23);
    const float* conv9_b = F(24);
    const float* fuse_b  = F(25);
    const float* se_b1   = F(26);
    const float* se_b2   = F(27);
    const float* l1f_b   = F(28);
    const float* l1b_b   = F(29);
    const float* l2f_b   = F(30);
    const float* l2b_b   = F(31);
    const float* bq      = F(32);
    const float* bk      = F(33);
    const float* bv      = F(34);
    const float* bo      = F(35);
    const float* d1_b    = F(36);
    const float* d2_b    = F(37);
    const float* d3_b    = F(38);
    const float* bn5_g = F(39), *bn5_b = F(40), *bn5_m = F(41), *bn5_v = F(42);
    const float* bn7_g = F(43), *bn7_b = F(44), *bn7_m = F(45), *bn7_v = F(46);
    const float* bn9_g = F(47), *bn9_b = F(48), *bn9_m = F(49), *bn9_v = F(50);
    const float* bnl1_g = F(51), *bnl1_b = F(52), *bnl1_m = F(53), *bnl1_v = F(54);
    const float* bnl2_g = F(55), *bnl2_b = F(56), *bnl2_m = F(57), *bnl2_v = F(58);
    const float* bnd1_g = F(59), *bnd1_b = F(60), *bnd1_m = F(61), *bnd1_v = F(62);
    const float* bnd2_g = F(63), *bnd2_b = F(64), *bnd2_m = F(65), *bnd2_v = F(66);
    #undef F

    float* ws = (float*)d_ws;
    // ---- re-planned layout (floats; total budget 37,748,736 = 151 MB) ----
    // PERMANENT prepped weights at top: [37556224, 37748736)
    unsigned short* wbB = (unsigned short*)(ws + 37556224);
    unsigned short* l1fkb = wbB;             // [4][32][64][8]  = 65536
    unsigned short* l1bkb = wbB + 65536;
    unsigned short* l2fkb = wbB + 131072;    // [8][16][64][8]  = 65536
    unsigned short* l2bkb = wbB + 196608;
    unsigned short* wqb   = wbB + 262144;    // [4][16][64][8]  = 32768
    unsigned short* wkb   = wbB + 294912;
    unsigned short* wvb   = wbB + 327680;
    unsigned short* fusewb= wbB + 360448;    // [6][8][64][8]   = 24576
    // phase buffers
    unsigned short* xbf   = (unsigned short*)(ws);                 // [0, 6488064)
    unsigned short* wfrag = (unsigned short*)(ws + 6488064);       // [6488064, 6529536)
    float* biascat = ws + 6529536;
    float* cscale  = ws + 6529728;
    float* cshift  = ws + 6529920;
    float* concat  = ws + 6530112;                                 // fp32 [6530112, 19113024)
    unsigned short* fusedbf = (unsigned short*)(ws + 19113024);    // [19113024, 21210176)
    float* e       = ws + 21210176;                                // [21210176, 21275712)
    unsigned short* xp1f  = (unsigned short*)(ws);                 // [0, 8388608)
    unsigned short* xp1b  = (unsigned short*)(ws + 8388608);       // [8388608, 16777216)
    unsigned short* l1out = (unsigned short*)(ws + 21275712);      // [21275712, 25470016)
    unsigned short* xp2f  = (unsigned short*)(ws);                 // [0, 2097152)
    unsigned short* xp2b  = (unsigned short*)(ws + 2097152);       // [2097152, 4194304)
    unsigned short* l2out = (unsigned short*)(ws + 4194304);       // [4194304, 8388608)
    unsigned short* qbuf  = (unsigned short*)(ws + 8388608);       // [8388608, 16777216)
    unsigned short* kbuf  = (unsigned short*)(ws + 16777216);      // [16777216, 25165824)
    unsigned short* vbuf  = (unsigned short*)(ws + 25165824);      // [25165824, 33554432)
    float* msum   = ws;                                            // [0, 131072)
    float* outp   = (float*)d_out;

    // ---- preps ----
    prep_x<<<dim3(512), dim3(256), 0, stream>>>(x, xbf);
    prep_w<<<dim3(81), dim3(256), 0, stream>>>(conv5_w, conv7_w, conv9_w, wfrag);
    prep_ss<<<dim3(1), dim3(192), 0, stream>>>(
        conv5_b, conv7_b, conv9_b,
        bn5_g, bn5_b, bn5_m, bn5_v,
        bn7_g, bn7_b, bn7_m, bn7_v,
        bn9_g, bn9_b, bn9_m, bn9_v,
        biascat, cscale, cshift);
    prep_wb<<<dim3(32), dim3(256), 0, stream>>>(l1f_k, l1fkb, 128, 512);
    prep_wb<<<dim3(32), dim3(256), 0, stream>>>(l1b_k, l1bkb, 128, 512);
    prep_wb<<<dim3(32), dim3(256), 0, stream>>>(l2f_k, l2fkb, 256, 256);
    prep_wb<<<dim3(32), dim3(256), 0, stream>>>(l2b_k, l2bkb, 256, 256);
    prep_wb<<<dim3(16), dim3(256), 0, stream>>>(wq, wqb, 128, 256);
    prep_wb<<<dim3(16), dim3(256), 0, stream>>>(wk, wkb, 128, 256);
    prep_wb<<<dim3(16), dim3(256), 0, stream>>>(wv, wvb, 128, 256);
    prep_wb<<<dim3(12), dim3(256), 0, stream>>>(fuse_w, fusewb, 192, 128);

    // ---- conv + fuse + SE ----
    conv_mfma<<<dim3(512,4), dim3(256), 0, stream>>>(
        xbf, wfrag, biascat, cscale, cshift, concat);
    xp_gemm2<192,false,false><<<dim3(512,1), dim3(256), 0, stream>>>(
        concat, fusewb, fusewb, fusewb, fuse_b, fuse_b, fuse_b,
        fusedbf, fusedbf, fusedbf, nullptr, 128, 1, 0, 0, 0);
    se_mean<<<dim3(512), dim3(128), 0, stream>>>(fusedbf, se_w1, se_b1, se_w2, se_b2, e);

    // ---- BiLSTM 1 ----
    xp_gemm2<128,true,true><<<dim3(512,8), dim3(256), 0, stream>>>(
        fusedbf, l1fkb, l1bkb, l1bkb, l1f_b, l1b_b, l1b_b,
        xp1f, xp1b, xp1b, e, 512, 4, 2, 2, 2);
    lstm_rec6<128><<<dim3(32), dim3(1024), 0, stream>>>(
        xp1f, xp1b, l1f_r, l1b_r, bnl1_g, bnl1_b, bnl1_m, bnl1_v, l1out);

    // ---- BiLSTM 2 ----
    xp_gemm2<256,true,false><<<dim3(512,4), dim3(256), 0, stream>>>(
        l1out, l2fkb, l2bkb, l2bkb, l2f_b, l2b_b, l2b_b,
        xp2f, xp2b, xp2b, nullptr, 256, 2, 2, 2, 2);
    lstm_rec6<64><<<dim3(32), dim3(512), 0, stream>>>(
        xp2f, xp2b, l2f_r, l2b_r, bnl2_g, bnl2_b, bnl2_m, bnl2_v, l2out);

    // ---- QKV merged (V head-transposed) ----
    xp_gemm2<128,true,false><<<dim3(512,6), dim3(256), 0, stream>>>(
        l2out, wqb, wkb, wvb, bq, bk, bv,
        qbuf, kbuf, vbuf, nullptr, 256, 2, 0, 0, 1);

    // ---- attention + head ----
    attn_kernel<<<dim3(512,8), dim3(256), 0, stream>>>(qbuf, kbuf, vbuf, msum);
    head_kernel<<<dim3(512), dim3(256), 0, stream>>>(
        msum, wo, bo,
        d1_w, d1_b, bnd1_g, bnd1_b, bnd1_m, bnd1_v,
        d2_w, d2_b, bnd2_g, bnd2_b, bnd2_m, bnd2_v,
        d3_w, d3_b, outp);

    (void)in_sizes; (void)n_in; (void)out_size; (void)ws_size;
}

// Round 12
// 932.054 us; speedup vs baseline: 1.2841x; 1.2841x over previous
//
#include <hip/hip_runtime.h>

#define EPS 1e-3f

typedef __attribute__((ext_vector_type(8))) short bf16x8;
typedef __attribute__((ext_vector_type(4))) float f32x4;

__device__ __forceinline__ float sigm(float x){ return 1.0f/(1.0f + __expf(-x)); }
__device__ __forceinline__ float tanhfast(float x){ return 1.0f - 2.0f/(1.0f + __expf(2.0f*x)); }

__device__ __forceinline__ unsigned short f2b(float f){
    union { float f; unsigned u; } v; v.f = f;
    unsigned r = v.u + 0x7FFFu + ((v.u >> 16) & 1u);
    return (unsigned short)(r >> 16);
}
__device__ __forceinline__ float b2f(unsigned short h){
    union { unsigned u; float f; } v; v.u = ((unsigned)h) << 16; return v.f;
}

// ---------------- prep: x fp32 [512,256,78] -> bf16 zero-padded [512,264,96] ----------------
__global__ void __launch_bounds__(256)
prep_x(const float* __restrict__ x, unsigned short* __restrict__ xbf)
{
    const int b = blockIdx.x;
    const float* xs = x + (size_t)b*256*78;
    unsigned short* xd = xbf + (size_t)b*264*96;
    for (int p = threadIdx.x; p < 264*48; p += 256){
        int row = p / 48;
        int cp  = (p - row*48) * 2;
        int t   = row - 4;
        unsigned short v0 = 0, v1 = 0;
        if (t >= 0 && t < 256){
            if (cp   < 78) v0 = f2b(xs[t*78 + cp]);
            if (cp+1 < 78) v1 = f2b(xs[t*78 + cp + 1]);
        }
        *(unsigned int*)(xd + row*96 + cp) = (unsigned)v0 | ((unsigned)v1 << 16);
    }
}

// ---------------- prep: unified conv weights -> bf16 B-fragment layout [27][12][512] ----------------
__global__ void __launch_bounds__(256)
prep_w(const float* __restrict__ w5, const float* __restrict__ w7, const float* __restrict__ w9,
       unsigned short* __restrict__ wfrag)
{
    int g = blockIdx.x*256 + threadIdx.x;
    if (g >= 27*12*64) return;
    union { unsigned short s[8]; uint4 v; } u;
    int base = g * 8;
    #pragma unroll
    for (int e = 0; e < 8; ++e){
        int lin  = base + e;
        int slot = lin & 511;
        int fi   = lin >> 9;
        int nt   = fi % 12, kcs = fi / 12;
        int k    = kcs / 3, cs = kcs - k*3;
        int l15  = slot >> 5, r = slot & 31;
        int lg   = r >> 3, ee = r & 7;
        int ci   = cs*32 + lg*8 + ee;
        int co   = nt*16 + l15;
        float val = 0.f;
        if (ci < 78){
            if (co < 64){
                int kk = k - 2;
                if (kk >= 0 && kk < 5) val = w5[(kk*78 + ci)*64 + co];
            } else if (co < 128){
                int kk = k - 1;
                if (kk >= 0 && kk < 7) val = w7[(kk*78 + ci)*64 + (co - 64)];
            } else {
                val = w9[(k*78 + ci)*64 + (co - 128)];
            }
        }
        u.s[e] = f2b(val);
    }
    *(uint4*)(wfrag + base) = u.v;
}

// ---------------- prep: generic W[K,N] fp32 -> bf16 B-fragment layout [K/32][N/16][64][8] ----------------
__global__ void __launch_bounds__(256)
prep_wb(const float* __restrict__ W, unsigned short* __restrict__ dst, int K, int N)
{
    int idx = blockIdx.x*256 + threadIdx.x;
    int NT = N >> 4;
    int total = (K >> 5) * NT * 64;
    if (idx >= total) return;
    int l   = idx & 63;
    int rem = idx >> 6;
    int ntg = rem % NT;
    int ks  = rem / NT;
    union { unsigned short s[8]; uint4 v; } u;
    #pragma unroll
    for (int e = 0; e < 8; ++e)
        u.s[e] = f2b(W[(size_t)(ks*32 + (l>>4)*8 + e)*N + ntg*16 + (l&15)]);
    *(uint4*)(dst + (size_t)idx*8) = u.v;
}

// ---------------- prep: fold conv bias + BN ----------------
__global__ void prep_ss(const float* b5, const float* b7, const float* b9,
                        const float* g5, const float* be5, const float* m5, const float* v5,
                        const float* g7, const float* be7, const float* m7, const float* v7,
                        const float* g9, const float* be9, const float* m9, const float* v9,
                        float* __restrict__ biascat, float* __restrict__ scale, float* __restrict__ shift)
{
    int c = threadIdx.x;
    if (c >= 192) return;
    float bv, g, be, m, v;
    if (c < 64){        bv=b5[c];      g=g5[c];      be=be5[c];      m=m5[c];      v=v5[c]; }
    else if (c < 128){  int i=c-64;  bv=b7[i]; g=g7[i]; be=be7[i]; m=m7[i]; v=v7[i]; }
    else {              int i=c-128; bv=b9[i]; g=g9[i]; be=be9[i]; m=m9[i]; v=v9[i]; }
    float s = g * rsqrtf(v + EPS);
    biascat[c] = bv;
    scale[c]   = s;
    shift[c]   = be - m*s;
}

// ---------------- fused 3-conv MFMA GEMM + relu + BN + maxpool2 -> concat [512,128,192] ----------------
__global__ void __launch_bounds__(256)
conv_mfma(const unsigned short* __restrict__ xbf,
          const unsigned short* __restrict__ wfrag,
          const float* __restrict__ biascat, const float* __restrict__ scale,
          const float* __restrict__ shift,
          float* __restrict__ out)
{
    const int b = blockIdx.x, tile = blockIdx.y;
    const int tid = threadIdx.x, lane = tid & 63, wv = tid >> 6;
    const int l15 = lane & 15, lg = lane >> 4;
    const int nt0 = wv * 3;
    const int t0  = tile * 64;

    f32x4 acc[4][3];
    #pragma unroll
    for (int nt = 0; nt < 3; ++nt){
        float bv = biascat[(nt0 + nt)*16 + l15];
        #pragma unroll
        for (int mt = 0; mt < 4; ++mt)
            acc[mt][nt] = (f32x4){bv, bv, bv, bv};
    }

    const unsigned short* xb = xbf + ((size_t)b*264 + t0 + l15)*96 + lg*8;
    const unsigned short* wb = wfrag + (size_t)nt0*512 + l15*32 + lg*8;

    for (int k = 0; k < 9; ++k){
        #pragma unroll
        for (int cs = 0; cs < 3; ++cs){
            bf16x8 A[4], Bf[3];
            #pragma unroll
            for (int mt = 0; mt < 4; ++mt)
                A[mt] = *(const bf16x8*)(xb + (size_t)(k + mt*16)*96 + cs*32);
            #pragma unroll
            for (int nt = 0; nt < 3; ++nt)
                Bf[nt] = *(const bf16x8*)(wb + (size_t)((k*3 + cs)*12 + nt)*512);
            #pragma unroll
            for (int mt = 0; mt < 4; ++mt)
                #pragma unroll
                for (int nt = 0; nt < 3; ++nt)
                    acc[mt][nt] = __builtin_amdgcn_mfma_f32_16x16x32_bf16(A[mt], Bf[nt], acc[mt][nt], 0, 0, 0);
        }
    }

    #pragma unroll
    for (int nt = 0; nt < 3; ++nt){
        int col = (nt0 + nt)*16 + l15;
        float s = scale[col], sh = shift[col];
        #pragma unroll
        for (int mt = 0; mt < 4; ++mt){
            float v0 = fmaxf(acc[mt][nt][0], 0.f)*s + sh;
            float v1 = fmaxf(acc[mt][nt][1], 0.f)*s + sh;
            float v2 = fmaxf(acc[mt][nt][2], 0.f)*s + sh;
            float v3 = fmaxf(acc[mt][nt][3], 0.f)*s + sh;
            int tb = tile*32 + mt*8 + lg*2;
            out[((size_t)b*128 + tb    )*192 + col] = fmaxf(v0, v1);
            out[((size_t)b*128 + tb + 1)*192 + col] = fmaxf(v2, v3);
        }
    }
}

// ---------------- SE: compute e[512][128] only ----------------
__global__ void __launch_bounds__(128)
se_mean(const unsigned short* __restrict__ fb,
        const float* __restrict__ w1, const float* __restrict__ b1,
        const float* __restrict__ w2, const float* __restrict__ b2,
        float* __restrict__ e)
{
    int b = blockIdx.x, c = threadIdx.x;
    __shared__ float sv[128];
    __shared__ float rv[8];
    const unsigned short* fp = fb + (size_t)b*128*128 + c;
    float acc = 0.f;
    for (int t = 0; t < 128; ++t) acc += b2f(fp[t*128]);
    sv[c] = acc * (1.f/128.f);
    __syncthreads();
    if (c < 8){
        float r = b1[c];
        for (int i = 0; i < 128; ++i) r = fmaf(sv[i], w1[i*8 + c], r);
        rv[c] = fmaxf(r, 0.f);
    }
    __syncthreads();
    float ev = b2[c];
    #pragma unroll
    for (int j = 0; j < 8; ++j) ev = fmaf(rv[j], w2[j*128 + c], ev);
    e[(size_t)b*128 + c] = sigm(ev);
}

// ---------------- xp_gemm2: A[M,K] @ Wsel[K,N] + bias, bf16 out; B prepped frag layout, A dbuf ----------------
template<int K, bool ABF16, bool ESCALE>
__global__ void __launch_bounds__(256)
xp_gemm2(const void* __restrict__ Av,
         const unsigned short* __restrict__ W0, const unsigned short* __restrict__ W1, const unsigned short* __restrict__ W2,
         const float* __restrict__ b0p, const float* __restrict__ b1p, const float* __restrict__ b2p,
         unsigned short* __restrict__ o0, unsigned short* __restrict__ o1, unsigned short* __restrict__ o2,
         const float* __restrict__ esc,
         int N, int yper, int om0, int om1, int om2)
{
    constexpr int KS = K/32;
    __shared__ unsigned short Asm[2][128][40];
    __shared__ float esm[ESCALE ? K : 1];

    const int tid = threadIdx.x, lane = tid & 63, wv = tid >> 6;
    const int wm = wv & 1, wn = wv >> 1;
    const size_t m0 = (size_t)blockIdx.x * 128;
    const int sel = blockIdx.y / yper;
    const int n0  = (blockIdx.y - sel*yper) * 128;
    const unsigned short* W = (sel == 0) ? W0 : (sel == 1 ? W1 : W2);
    const float* bias       = (sel == 0) ? b0p : (sel == 1 ? b1p : b2p);
    unsigned short* outp    = (sel == 0) ? o0 : (sel == 1 ? o1 : o2);
    const int om            = (sel == 0) ? om0 : (sel == 1 ? om1 : om2);
    const int NTf = N >> 4;

    if constexpr (ESCALE){
        for (int i = tid; i < K; i += 256) esm[i] = esc[(size_t)blockIdx.x*K + i];
        __syncthreads();
    }

    auto stage = [&](int bq, int ksl){
        const int k0 = ksl*32;
        if constexpr (!ABF16){
            const float* Ag = (const float*)Av;
            #pragma unroll
            for (int i = 0; i < 2; ++i){
                int g = tid + i*256;
                int r = g >> 2, c8 = g & 3;
                float4 d0 = *(const float4*)(Ag + (m0 + r)*K + k0 + c8*8);
                float4 d1 = *(const float4*)(Ag + (m0 + r)*K + k0 + c8*8 + 4);
                union { unsigned short s[8]; uint4 v; } u;
                u.s[0]=f2b(d0.x); u.s[1]=f2b(d0.y); u.s[2]=f2b(d0.z); u.s[3]=f2b(d0.w);
                u.s[4]=f2b(d1.x); u.s[5]=f2b(d1.y); u.s[6]=f2b(d1.z); u.s[7]=f2b(d1.w);
                *(uint4*)&Asm[bq][r][c8*8] = u.v;
            }
        } else {
            const unsigned short* Ag = (const unsigned short*)Av;
            #pragma unroll
            for (int i = 0; i < 2; ++i){
                int g = tid + i*256;
                int r = g >> 2, c8 = g & 3;
                uint4 d = *(const uint4*)(Ag + (m0 + r)*K + k0 + c8*8);
                if constexpr (ESCALE){
                    unsigned short* s = (unsigned short*)&d;
                    #pragma unroll
                    for (int j = 0; j < 8; ++j)
                        s[j] = f2b(b2f(s[j]) * esm[k0 + c8*8 + j]);
                }
                *(uint4*)&Asm[bq][r][c8*8] = d;
            }
        }
    };

    f32x4 acc[4][4];
    #pragma unroll
    for (int nt = 0; nt < 4; ++nt){
        float bv = bias[n0 + wn*64 + nt*16 + (lane & 15)];
        #pragma unroll
        for (int mt = 0; mt < 4; ++mt)
            acc[mt][nt] = (f32x4){bv, bv, bv, bv};
    }

    stage(0, 0);
    __syncthreads();

    int buf = 0;
    for (int ks = 0; ks < KS; ++ks){
        if (ks + 1 < KS) stage(buf ^ 1, ks + 1);

        bf16x8 af[4], bfr[4];
        #pragma unroll
        for (int mt = 0; mt < 4; ++mt)
            af[mt] = *(const bf16x8*)&Asm[buf][wm*64 + mt*16 + (lane & 15)][(lane >> 4)*8];
        #pragma unroll
        for (int nt = 0; nt < 4; ++nt){
            int ntg = (n0 >> 4) + wn*4 + nt;
            bfr[nt] = *(const bf16x8*)(W + ((size_t)(ks*NTf + ntg)*64 + lane)*8);
        }
        #pragma unroll
        for (int mt = 0; mt < 4; ++mt)
            #pragma unroll
            for (int nt = 0; nt < 4; ++nt)
                acc[mt][nt] = __builtin_amdgcn_mfma_f32_16x16x32_bf16(af[mt], bfr[nt], acc[mt][nt], 0, 0, 0);
        __syncthreads();
        buf ^= 1;
    }

    const int Uq = N >> 2;
    #pragma unroll
    for (int mt = 0; mt < 4; ++mt)
        #pragma unroll
        for (int nt = 0; nt < 4; ++nt)
            #pragma unroll
            for (int r = 0; r < 4; ++r){
                size_t row = m0 + wm*64 + mt*16 + (lane >> 4)*4 + r;
                int    col = n0 + wn*64 + nt*16 + (lane & 15);
                unsigned short val = f2b(acc[mt][nt][r]);
                if (om == 0){
                    outp[row*N + col] = val;
                } else if (om == 1){
                    size_t off = ((size_t)((row >> 7)*8 + (col >> 5))*32 + (col & 31))*128 + (row & 127);
                    outp[off] = val;
                } else {
                    outp[row*N + (col & (Uq-1))*4 + (col / Uq)] = val;
                }
            }
}

// ---------------- LSTM recurrence v7: v5 structure + prepped bf16 R fragments (no per-step f2b) ----------------
// Wave wv owns units wv*16+l15, all 4 gates; RB=16 rows; all lanes do gate math for 4 rows; c in regs;
// h double-buffered in LDS; raw lgkmcnt-barrier per step. R frags are vector loads from prepped buffer.
template<int U>
__global__ void __launch_bounds__(4*U, 2)
lstm_rec7(const unsigned short* __restrict__ xpf, const unsigned short* __restrict__ xpb,
          const unsigned short* __restrict__ Rff, const unsigned short* __restrict__ Rbf,
          const float* __restrict__ bng, const float* __restrict__ bnb,
          const float* __restrict__ bnm, const float* __restrict__ bnv,
          unsigned short* __restrict__ outv)
{
    constexpr int Z  = 4*U;
    constexpr int KT = U/32;
    constexpr int HP = U + 8;
    constexpr int NT = Z/16;
    constexpr int UG = U/16;

    __shared__ unsigned short h_lds[2][16][HP];

    const int tid = threadIdx.x, lane = tid & 63, wv = tid >> 6;
    const int l15 = lane & 15, lg = lane >> 4;
    const int dir = blockIdx.y;
    const int b0  = blockIdx.x * 16;

    const unsigned short* xp = dir ? xpb : xpf;
    const unsigned short* Rfp = dir ? Rbf : Rff;

    for (int i = tid; i < 2*16*HP; i += 4*U) ((unsigned short*)h_lds)[i] = 0;

    // rf[kt][g] = prepped frag at ntg = g*UG + wv (vector load, no conversion)
    bf16x8 rf[KT][4];
    #pragma unroll
    for (int kt = 0; kt < KT; ++kt)
        #pragma unroll
        for (int g = 0; g < 4; ++g)
            rf[kt][g] = *(const bf16x8*)(Rfp + (((size_t)kt*NT + g*UG + wv)*64 + lane)*8);

    const int u_ = wv*16 + l15;
    const int ch = dir*U + u_;
    const float bns  = bng[ch] * rsqrtf(bnv[ch] + EPS);
    const float bnsh = bnb[ch] - bnm[ch]*bns;
    float cst[4] = {0.f, 0.f, 0.f, 0.f};
    const unsigned short* xbase = xp + ((size_t)(b0 + lg*4)*128)*Z + u_*4;

    ushort4 xq[4];
    {
        const int tf = dir ? 127 : 0;
        #pragma unroll
        for (int r = 0; r < 4; ++r)
            xq[r] = *(const ushort4*)(xbase + ((size_t)r*128 + tf)*Z);
    }
    __syncthreads();

    int buf = 0;
    for (int ts = 0; ts < 128; ++ts){
        const int t = dir ? 127 - ts : ts;
        ushort4 xn[4] = {};
        if (ts < 127){
            const int tn = dir ? t - 1 : t + 1;
            #pragma unroll
            for (int r = 0; r < 4; ++r)
                xn[r] = *(const ushort4*)(xbase + ((size_t)r*128 + tn)*Z);
        }
        bf16x8 af[KT];
        #pragma unroll
        for (int kt = 0; kt < KT; ++kt)
            af[kt] = *(const bf16x8*)&h_lds[buf][l15][kt*32 + lg*8];
        f32x4 acc[4];
        #pragma unroll
        for (int g = 0; g < 4; ++g) acc[g] = (f32x4){0.f,0.f,0.f,0.f};
        #pragma unroll
        for (int kt = 0; kt < KT; ++kt)
            #pragma unroll
            for (int g = 0; g < 4; ++g)
                acc[g] = __builtin_amdgcn_mfma_f32_16x16x32_bf16(af[kt], rf[kt][g], acc[g], 0, 0, 0);
        #pragma unroll
        for (int r = 0; r < 4; ++r){
            float zi = acc[0][r] + b2f(xq[r].x);
            float zf = acc[1][r] + b2f(xq[r].y);
            float zg = acc[2][r] + b2f(xq[r].z);
            float zo = acc[3][r] + b2f(xq[r].w);
            float c  = sigm(zf)*cst[r] + sigm(zi)*tanhfast(zg);
            cst[r] = c;
            float h = sigm(zo)*tanhfast(c);
            h_lds[buf^1][lg*4 + r][u_] = f2b(h);
            size_t oidx = ((size_t)(b0 + lg*4 + r)*128 + t)*(size_t)(2*U) + ch;
            outv[oidx] = f2b(fmaf(h, bns, bnsh));
        }
        asm volatile("s_waitcnt lgkmcnt(0)" ::: "memory");
        __builtin_amdgcn_s_barrier();
        buf ^= 1;
        #pragma unroll
        for (int r = 0; r < 4; ++r) xq[r] = xn[r];
    }
}

// ---------------- MFMA attention per (b, head) ----------------
__global__ void __launch_bounds__(256)
attn_kernel(const unsigned short* __restrict__ qb,
            const unsigned short* __restrict__ kb,
            const unsigned short* __restrict__ vb,
            float* __restrict__ msum)
{
    __shared__ unsigned short p_lds[128][136];
    __shared__ float red[4][2][16];

    const int b  = blockIdx.x, hd = blockIdx.y;
    const int tid = threadIdx.x, lane = tid & 63, wv = tid >> 6;
    const int m0 = wv * 32;
    const int l15 = lane & 15, lg = lane >> 4;

    bf16x8 aq[2];
    #pragma unroll
    for (int mt = 0; mt < 2; ++mt)
        aq[mt] = *(const bf16x8*)(qb + ((size_t)(b*128 + m0 + mt*16 + l15))*256 + hd*32 + lg*8);

    bf16x8 bk[8];
    #pragma unroll
    for (int nt = 0; nt < 8; ++nt)
        bk[nt] = *(const bf16x8*)(kb + ((size_t)(b*128 + nt*16 + l15))*256 + hd*32 + lg*8);

    f32x4 s[2][8];
    #pragma unroll
    for (int mt = 0; mt < 2; ++mt)
        #pragma unroll
        for (int nt = 0; nt < 8; ++nt) s[mt][nt] = (f32x4){0.f,0.f,0.f,0.f};
    #pragma unroll
    for (int mt = 0; mt < 2; ++mt)
        #pragma unroll
        for (int nt = 0; nt < 8; ++nt)
            s[mt][nt] = __builtin_amdgcn_mfma_f32_16x16x32_bf16(aq[mt], bk[nt], s[mt][nt], 0, 0, 0);

    const float scale = 0.17677669529663687f;
    #pragma unroll
    for (int mt = 0; mt < 2; ++mt)
        #pragma unroll
        for (int r = 0; r < 4; ++r){
            float mx = -1e30f;
            #pragma unroll
            for (int nt = 0; nt < 8; ++nt) mx = fmaxf(mx, s[mt][nt][r]);
            #pragma unroll
            for (int msk = 1; msk < 16; msk <<= 1) mx = fmaxf(mx, __shfl_xor(mx, msk, 64));
            float pv[8], sum = 0.f;
            #pragma unroll
            for (int nt = 0; nt < 8; ++nt){
                pv[nt] = __expf((s[mt][nt][r] - mx) * scale);
                sum += pv[nt];
            }
            #pragma unroll
            for (int msk = 1; msk < 16; msk <<= 1) sum += __shfl_xor(sum, msk, 64);
            float inv = 1.f / sum;
            int row = m0 + mt*16 + lg*4 + r;
            #pragma unroll
            for (int nt = 0; nt < 8; ++nt)
                p_lds[row][nt*16 + l15] = f2b(pv[nt] * inv);
        }
    __syncthreads();

    f32x4 o[2][2];
    #pragma unroll
    for (int mt = 0; mt < 2; ++mt)
        #pragma unroll
        for (int dn = 0; dn < 2; ++dn) o[mt][dn] = (f32x4){0.f,0.f,0.f,0.f};
    bf16x8 bv[4][2];
    #pragma unroll
    for (int kt = 0; kt < 4; ++kt)
        #pragma unroll
        for (int dn = 0; dn < 2; ++dn)
            bv[kt][dn] = *(const bf16x8*)(vb + ((size_t)(b*8 + hd)*32 + dn*16 + l15)*128 + kt*32 + lg*8);
    #pragma unroll
    for (int mt = 0; mt < 2; ++mt)
        #pragma unroll
        for (int kt = 0; kt < 4; ++kt){
            bf16x8 ap = *(const bf16x8*)&p_lds[m0 + mt*16 + l15][kt*32 + lg*8];
            #pragma unroll
            for (int dn = 0; dn < 2; ++dn)
                o[mt][dn] = __builtin_amdgcn_mfma_f32_16x16x32_bf16(ap, bv[kt][dn], o[mt][dn], 0, 0, 0);
        }

    float sm[2];
    #pragma unroll
    for (int dn = 0; dn < 2; ++dn){
        float a = 0.f;
        #pragma unroll
        for (int mt = 0; mt < 2; ++mt)
            #pragma unroll
            for (int r = 0; r < 4; ++r) a += o[mt][dn][r];
        a += __shfl_xor(a, 16, 64);
        a += __shfl_xor(a, 32, 64);
        sm[dn] = a;
    }
    if (lg == 0){
        red[wv][0][l15] = sm[0];
        red[wv][1][l15] = sm[1];
    }
    __syncthreads();
    if (tid < 32){
        int dn = tid >> 4, n = tid & 15;
        float tot = red[0][dn][n] + red[1][dn][n] + red[2][dn][n] + red[3][dn][n];
        msum[(size_t)b*256 + hd*32 + dn*16 + n] = tot * (1.f/128.f);
    }
}

// ---------------- head ----------------
__global__ void __launch_bounds__(256)
head_kernel(const float* __restrict__ msum,
            const float* __restrict__ wo, const float* __restrict__ bo,
            const float* __restrict__ d1w, const float* __restrict__ d1b,
            const float* __restrict__ g1, const float* __restrict__ b1,
            const float* __restrict__ m1, const float* __restrict__ v1,
            const float* __restrict__ d2w, const float* __restrict__ d2b,
            const float* __restrict__ g2, const float* __restrict__ b2,
            const float* __restrict__ m2, const float* __restrict__ v2,
            const float* __restrict__ d3w, const float* __restrict__ d3b,
            float* __restrict__ outp)
{
    int b = blockIdx.x, j = threadIdx.x;
    __shared__ float s1[256];
    __shared__ float s2[256];
    const float* mr = msum + (size_t)b*256;
    float acc = bo[j];
    #pragma unroll 4
    for (int i = 0; i < 256; ++i) acc = fmaf(mr[i], wo[i*256 + j], acc);
    s1[j] = acc;
    __syncthreads();
    float a1 = d1b[j];
    #pragma unroll 4
    for (int i = 0; i < 256; ++i) a1 = fmaf(s1[i], d1w[i*256 + j], a1);
    a1 = fmaxf(a1, 0.f);
    float sc1 = g1[j] * rsqrtf(v1[j] + EPS);
    a1 = a1 * sc1 + (b1[j] - m1[j] * sc1);
    s2[j] = a1;
    __syncthreads();
    if (j < 128){
        float a2 = d2b[j];
        #pragma unroll 4
        for (int i = 0; i < 256; ++i) a2 = fmaf(s2[i], d2w[i*128 + j], a2);
        a2 = fmaxf(a2, 0.f);
        float sc2 = g2[j] * rsqrtf(v2[j] + EPS);
        a2 = a2 * sc2 + (b2[j] - m2[j] * sc2);
        s1[j] = a2;
    }
    __syncthreads();
    if (j == 0){
        float a3 = d3b[0];
        for (int i = 0; i < 128; ++i) a3 = fmaf(s1[i], d3w[i], a3);
        outp[b] = sigm(a3);
    }
}

extern "C" void kernel_launch(void* const* d_in, const int* in_sizes, int n_in,
                              void* d_out, int out_size, void* d_ws, size_t ws_size,
                              hipStream_t stream)
{
    #define F(i) ((const float*)d_in[i])
    const float* x       = F(0);
    const float* conv5_w = F(1);
    const float* conv7_w = F(2);
    const float* conv9_w = F(3);
    const float* fuse_w  = F(4);
    const float* se_w1   = F(5);
    const float* se_w2   = F(6);
    const float* l1f_k   = F(7);
    const float* l1f_r   = F(8);
    const float* l1b_k   = F(9);
    const float* l1b_r   = F(10);
    const float* l2f_k   = F(11);
    const float* l2f_r   = F(12);
    const float* l2b_k   = F(13);
    const float* l2b_r   = F(14);
    const float* wq      = F(15);
    const float* wk      = F(16);
    const float* wv      = F(17);
    const float* wo      = F(18);
    const float* d1_w    = F(19);
    const float* d2_w    = F(20);
    const float* d3_w    = F(21);
    const float* conv5_b = F(22);
    const float* conv7_b = F(23);
    const float* conv9_b = F(24);
    const float* fuse_b  = F(25);
    const float* se_b1   = F(26);
    const float* se_b2   = F(27);
    const float* l1f_b   = F(28);
    const float* l1b_b   = F(29);
    const float* l2f_b   = F(30);
    const float* l2b_b   = F(31);
    const float* bq      = F(32);
    const float* bk      = F(33);
    const float* bv      = F(34);
    const float* bo      = F(35);
    const float* d1_b    = F(36);
    const float* d2_b    = F(37);
    const float* d3_b    = F(38);
    const float* bn5_g = F(39), *bn5_b = F(40), *bn5_m = F(41), *bn5_v = F(42);
    const float* bn7_g = F(43), *bn7_b = F(44), *bn7_m = F(45), *bn7_v = F(46);
    const float* bn9_g = F(47), *bn9_b = F(48), *bn9_m = F(49), *bn9_v = F(50);
    const float* bnl1_g = F(51), *bnl1_b = F(52), *bnl1_m = F(53), *bnl1_v = F(54);
    const float* bnl2_g = F(55), *bnl2_b = F(56), *bnl2_m = F(57), *bnl2_v = F(58);
    const float* bnd1_g = F(59), *bnd1_b = F(60), *bnd1_m = F(61), *bnd1_v = F(62);
    const float* bnd2_g = F(63), *bnd2_b = F(64), *bnd2_m = F(65), *bnd2_v = F(66);
    #undef F

    float* ws = (float*)d_ws;
    // ---- layout (floats; budget 37,748,736 = 151 MB) ----
    // PERMANENT prepped weights at top: [37474304, 37748736) = 274432 floats = 548864 shorts
    unsigned short* wbB = (unsigned short*)(ws + 37474304);
    unsigned short* l1fkb = wbB;             // [4][32][64][8]  = 65536 shorts
    unsigned short* l1bkb = wbB + 65536;
    unsigned short* l2fkb = wbB + 131072;    // [8][16][64][8]  = 65536
    unsigned short* l2bkb = wbB + 196608;
    unsigned short* wqb   = wbB + 262144;    // [4][16][64][8]  = 32768
    unsigned short* wkb   = wbB + 294912;
    unsigned short* wvb   = wbB + 327680;
    unsigned short* fusewb= wbB + 360448;    // [6][8][64][8]   = 24576
    unsigned short* l1frb = wbB + 385024;    // [4][32][64][8]  = 65536  (R: K=128,N=512)
    unsigned short* l1brb = wbB + 450560;
    unsigned short* l2frb = wbB + 516096;    // [2][16][64][8]  = 16384  (R: K=64,N=256)
    unsigned short* l2brb = wbB + 532480;    // ends 548864
    // phase buffers
    unsigned short* xbf   = (unsigned short*)(ws);                 // [0, 6488064) shorts
    unsigned short* wfrag = (unsigned short*)(ws + 6488064);
    float* biascat = ws + 6529536;
    float* cscale  = ws + 6529728;
    float* cshift  = ws + 6529920;
    float* concat  = ws + 6530112;                                 // fp32 12.58M
    unsigned short* fusedbf = (unsigned short*)(ws + 19113024);
    float* e       = ws + 21210176;
    unsigned short* xp1f  = (unsigned short*)(ws);
    unsigned short* xp1b  = (unsigned short*)(ws + 8388608);
    unsigned short* l1out = (unsigned short*)(ws + 21275712);
    unsigned short* xp2f  = (unsigned short*)(ws);
    unsigned short* xp2b  = (unsigned short*)(ws + 2097152);
    unsigned short* l2out = (unsigned short*)(ws + 4194304);
    unsigned short* qbuf  = (unsigned short*)(ws + 8388608);
    unsigned short* kbuf  = (unsigned short*)(ws + 16777216);
    unsigned short* vbuf  = (unsigned short*)(ws + 25165824);
    float* msum   = ws;
    float* outp   = (float*)d_out;

    // ---- preps ----
    prep_x<<<dim3(512), dim3(256), 0, stream>>>(x, xbf);
    prep_w<<<dim3(81), dim3(256), 0, stream>>>(conv5_w, conv7_w, conv9_w, wfrag);
    prep_ss<<<dim3(1), dim3(192), 0, stream>>>(
        conv5_b, conv7_b, conv9_b,
        bn5_g, bn5_b, bn5_m, bn5_v,
        bn7_g, bn7_b, bn7_m, bn7_v,
        bn9_g, bn9_b, bn9_m, bn9_v,
        biascat, cscale, cshift);
    prep_wb<<<dim3(32), dim3(256), 0, stream>>>(l1f_k, l1fkb, 128, 512);
    prep_wb<<<dim3(32), dim3(256), 0, stream>>>(l1b_k, l1bkb, 128, 512);
    prep_wb<<<dim3(32), dim3(256), 0, stream>>>(l2f_k, l2fkb, 256, 256);
    prep_wb<<<dim3(32), dim3(256), 0, stream>>>(l2b_k, l2bkb, 256, 256);
    prep_wb<<<dim3(16), dim3(256), 0, stream>>>(wq, wqb, 128, 256);
    prep_wb<<<dim3(16), dim3(256), 0, stream>>>(wk, wkb, 128, 256);
    prep_wb<<<dim3(16), dim3(256), 0, stream>>>(wv, wvb, 128, 256);
    prep_wb<<<dim3(12), dim3(256), 0, stream>>>(fuse_w, fusewb, 192, 128);
    prep_wb<<<dim3(32), dim3(256), 0, stream>>>(l1f_r, l1frb, 128, 512);
    prep_wb<<<dim3(32), dim3(256), 0, stream>>>(l1b_r, l1brb, 128, 512);
    prep_wb<<<dim3(8),  dim3(256), 0, stream>>>(l2f_r, l2frb, 64, 256);
    prep_wb<<<dim3(8),  dim3(256), 0, stream>>>(l2b_r, l2brb, 64, 256);

    // ---- conv + fuse + SE ----
    conv_mfma<<<dim3(512,4), dim3(256), 0, stream>>>(
        xbf, wfrag, biascat, cscale, cshift, concat);
    xp_gemm2<192,false,false><<<dim3(512,1), dim3(256), 0, stream>>>(
        concat, fusewb, fusewb, fusewb, fuse_b, fuse_b, fuse_b,
        fusedbf, fusedbf, fusedbf, nullptr, 128, 1, 0, 0, 0);
    se_mean<<<dim3(512), dim3(128), 0, stream>>>(fusedbf, se_w1, se_b1, se_w2, se_b2, e);

    // ---- BiLSTM 1 ----
    xp_gemm2<128,true,true><<<dim3(512,8), dim3(256), 0, stream>>>(
        fusedbf, l1fkb, l1bkb, l1bkb, l1f_b, l1b_b, l1b_b,
        xp1f, xp1b, xp1b, e, 512, 4, 2, 2, 2);
    lstm_rec7<128><<<dim3(32,2), dim3(512), 0, stream>>>(
        xp1f, xp1b, l1frb, l1brb, bnl1_g, bnl1_b, bnl1_m, bnl1_v, l1out);

    // ---- BiLSTM 2 ----
    xp_gemm2<256,true,false><<<dim3(512,4), dim3(256), 0, stream>>>(
        l1out, l2fkb, l2bkb, l2bkb, l2f_b, l2b_b, l2b_b,
        xp2f, xp2b, xp2b, nullptr, 256, 2, 2, 2, 2);
    lstm_rec7<64><<<dim3(32,2), dim3(256), 0, stream>>>(
        xp2f, xp2b, l2frb, l2brb, bnl2_g, bnl2_b, bnl2_m, bnl2_v, l2out);

    // ---- QKV merged (V head-transposed) ----
    xp_gemm2<128,true,false><<<dim3(512,6), dim3(256), 0, stream>>>(
        l2out, wqb, wkb, wvb, bq, bk, bv,
        qbuf, kbuf, vbuf, nullptr, 256, 2, 0, 0, 1);

    // ---- attention + head ----
    attn_kernel<<<dim3(512,8), dim3(256), 0, stream>>>(qbuf, kbuf, vbuf, msum);
    head_kernel<<<dim3(512), dim3(256), 0, stream>>>(
        msum, wo, bo,
        d1_w, d1_b, bnd1_g, bnd1_b, bnd1_m, bnd1_v,
        d2_w, d2_b, bnd2_g, bnd2_b, bnd2_m, bnd2_v,
        d3_w, d3_b, outp);

    (void)in_sizes; (void)n_in; (void)out_size; (void)ws_size;
}

// Round 13
// 740.326 us; speedup vs baseline: 1.6167x; 1.2590x over previous
//
#include <hip/hip_runtime.h>

#define EPS 1e-3f

typedef __attribute__((ext_vector_type(8))) short bf16x8;
typedef __attribute__((ext_vector_type(4))) float f32x4;

__device__ __forceinline__ float sigm(float x){ return 1.0f/(1.0f + __expf(-x)); }
__device__ __forceinline__ float tanhfast(float x){ return 1.0f - 2.0f/(1.0f + __expf(2.0f*x)); }

__device__ __forceinline__ unsigned short f2b(float f){
    union { float f; unsigned u; } v; v.f = f;
    unsigned r = v.u + 0x7FFFu + ((v.u >> 16) & 1u);
    return (unsigned short)(r >> 16);
}
__device__ __forceinline__ float b2f(unsigned short h){
    union { unsigned u; float f; } v; v.u = ((unsigned)h) << 16; return v.f;
}

// ---------------- prep: x fp32 [512,256,78] -> bf16 zero-padded [512,264,96] ----------------
__global__ void __launch_bounds__(256)
prep_x(const float* __restrict__ x, unsigned short* __restrict__ xbf)
{
    const int b = blockIdx.x;
    const float* xs = x + (size_t)b*256*78;
    unsigned short* xd = xbf + (size_t)b*264*96;
    for (int p = threadIdx.x; p < 264*48; p += 256){
        int row = p / 48;
        int cp  = (p - row*48) * 2;
        int t   = row - 4;
        unsigned short v0 = 0, v1 = 0;
        if (t >= 0 && t < 256){
            if (cp   < 78) v0 = f2b(xs[t*78 + cp]);
            if (cp+1 < 78) v1 = f2b(xs[t*78 + cp + 1]);
        }
        *(unsigned int*)(xd + row*96 + cp) = (unsigned)v0 | ((unsigned)v1 << 16);
    }
}

// ---------------- prep: unified conv weights -> bf16 B-fragment layout [27][12][512] ----------------
__global__ void __launch_bounds__(256)
prep_w(const float* __restrict__ w5, const float* __restrict__ w7, const float* __restrict__ w9,
       unsigned short* __restrict__ wfrag)
{
    int g = blockIdx.x*256 + threadIdx.x;
    if (g >= 27*12*64) return;
    union { unsigned short s[8]; uint4 v; } u;
    int base = g * 8;
    #pragma unroll
    for (int e = 0; e < 8; ++e){
        int lin  = base + e;
        int slot = lin & 511;
        int fi   = lin >> 9;
        int nt   = fi % 12, kcs = fi / 12;
        int k    = kcs / 3, cs = kcs - k*3;
        int l15  = slot >> 5, r = slot & 31;
        int lg   = r >> 3, ee = r & 7;
        int ci   = cs*32 + lg*8 + ee;
        int co   = nt*16 + l15;
        float val = 0.f;
        if (ci < 78){
            if (co < 64){
                int kk = k - 2;
                if (kk >= 0 && kk < 5) val = w5[(kk*78 + ci)*64 + co];
            } else if (co < 128){
                int kk = k - 1;
                if (kk >= 0 && kk < 7) val = w7[(kk*78 + ci)*64 + (co - 64)];
            } else {
                val = w9[(k*78 + ci)*64 + (co - 128)];
            }
        }
        u.s[e] = f2b(val);
    }
    *(uint4*)(wfrag + base) = u.v;
}

// ---------------- prep: generic W[K,N] fp32 -> bf16 B-fragment layout [K/32][N/16][64][8] ----------------
__global__ void __launch_bounds__(256)
prep_wb(const float* __restrict__ W, unsigned short* __restrict__ dst, int K, int N)
{
    int idx = blockIdx.x*256 + threadIdx.x;
    int NT = N >> 4;
    int total = (K >> 5) * NT * 64;
    if (idx >= total) return;
    int l   = idx & 63;
    int rem = idx >> 6;
    int ntg = rem % NT;
    int ks  = rem / NT;
    union { unsigned short s[8]; uint4 v; } u;
    #pragma unroll
    for (int e = 0; e < 8; ++e)
        u.s[e] = f2b(W[(size_t)(ks*32 + (l>>4)*8 + e)*N + ntg*16 + (l&15)]);
    *(uint4*)(dst + (size_t)idx*8) = u.v;
}

// ---------------- prep: fold conv bias + BN ----------------
__global__ void prep_ss(const float* b5, const float* b7, const float* b9,
                        const float* g5, const float* be5, const float* m5, const float* v5,
                        const float* g7, const float* be7, const float* m7, const float* v7,
                        const float* g9, const float* be9, const float* m9, const float* v9,
                        float* __restrict__ biascat, float* __restrict__ scale, float* __restrict__ shift)
{
    int c = threadIdx.x;
    if (c >= 192) return;
    float bv, g, be, m, v;
    if (c < 64){        bv=b5[c];      g=g5[c];      be=be5[c];      m=m5[c];      v=v5[c]; }
    else if (c < 128){  int i=c-64;  bv=b7[i]; g=g7[i]; be=be7[i]; m=m7[i]; v=v7[i]; }
    else {              int i=c-128; bv=b9[i]; g=g9[i]; be=be9[i]; m=m9[i]; v=v9[i]; }
    float s = g * rsqrtf(v + EPS);
    biascat[c] = bv;
    scale[c]   = s;
    shift[c]   = be - m*s;
}

// ---------------- fused 3-conv MFMA GEMM + relu + BN + maxpool2 -> concat [512,128,192] ----------------
__global__ void __launch_bounds__(256)
conv_mfma(const unsigned short* __restrict__ xbf,
          const unsigned short* __restrict__ wfrag,
          const float* __restrict__ biascat, const float* __restrict__ scale,
          const float* __restrict__ shift,
          float* __restrict__ out)
{
    const int b = blockIdx.x, tile = blockIdx.y;
    const int tid = threadIdx.x, lane = tid & 63, wv = tid >> 6;
    const int l15 = lane & 15, lg = lane >> 4;
    const int nt0 = wv * 3;
    const int t0  = tile * 64;

    f32x4 acc[4][3];
    #pragma unroll
    for (int nt = 0; nt < 3; ++nt){
        float bv = biascat[(nt0 + nt)*16 + l15];
        #pragma unroll
        for (int mt = 0; mt < 4; ++mt)
            acc[mt][nt] = (f32x4){bv, bv, bv, bv};
    }

    const unsigned short* xb = xbf + ((size_t)b*264 + t0 + l15)*96 + lg*8;
    const unsigned short* wb = wfrag + (size_t)nt0*512 + l15*32 + lg*8;

    for (int k = 0; k < 9; ++k){
        #pragma unroll
        for (int cs = 0; cs < 3; ++cs){
            bf16x8 A[4], Bf[3];
            #pragma unroll
            for (int mt = 0; mt < 4; ++mt)
                A[mt] = *(const bf16x8*)(xb + (size_t)(k + mt*16)*96 + cs*32);
            #pragma unroll
            for (int nt = 0; nt < 3; ++nt)
                Bf[nt] = *(const bf16x8*)(wb + (size_t)((k*3 + cs)*12 + nt)*512);
            #pragma unroll
            for (int mt = 0; mt < 4; ++mt)
                #pragma unroll
                for (int nt = 0; nt < 3; ++nt)
                    acc[mt][nt] = __builtin_amdgcn_mfma_f32_16x16x32_bf16(A[mt], Bf[nt], acc[mt][nt], 0, 0, 0);
        }
    }

    #pragma unroll
    for (int nt = 0; nt < 3; ++nt){
        int col = (nt0 + nt)*16 + l15;
        float s = scale[col], sh = shift[col];
        #pragma unroll
        for (int mt = 0; mt < 4; ++mt){
            float v0 = fmaxf(acc[mt][nt][0], 0.f)*s + sh;
            float v1 = fmaxf(acc[mt][nt][1], 0.f)*s + sh;
            float v2 = fmaxf(acc[mt][nt][2], 0.f)*s + sh;
            float v3 = fmaxf(acc[mt][nt][3], 0.f)*s + sh;
            int tb = tile*32 + mt*8 + lg*2;
            out[((size_t)b*128 + tb    )*192 + col] = fmaxf(v0, v1);
            out[((size_t)b*128 + tb + 1)*192 + col] = fmaxf(v2, v3);
        }
    }
}

// ---------------- SE: compute e[512][128] only ----------------
__global__ void __launch_bounds__(128)
se_mean(const unsigned short* __restrict__ fb,
        const float* __restrict__ w1, const float* __restrict__ b1,
        const float* __restrict__ w2, const float* __restrict__ b2,
        float* __restrict__ e)
{
    int b = blockIdx.x, c = threadIdx.x;
    __shared__ float sv[128];
    __shared__ float rv[8];
    const unsigned short* fp = fb + (size_t)b*128*128 + c;
    float acc = 0.f;
    for (int t = 0; t < 128; ++t) acc += b2f(fp[t*128]);
    sv[c] = acc * (1.f/128.f);
    __syncthreads();
    if (c < 8){
        float r = b1[c];
        for (int i = 0; i < 128; ++i) r = fmaf(sv[i], w1[i*8 + c], r);
        rv[c] = fmaxf(r, 0.f);
    }
    __syncthreads();
    float ev = b2[c];
    #pragma unroll
    for (int j = 0; j < 8; ++j) ev = fmaf(rv[j], w2[j*128 + c], ev);
    e[(size_t)b*128 + c] = sigm(ev);
}

// ---------------- xp GEMM (round-5 proven): out = A@W + bias, bf16 out ----------------
// OUTMODE 0: [M,N]. 1: V per-head-transpose. 2: gate-interleave [row][u][4] (U=N/4).
template<int K, bool ABF16, int OUTMODE, bool ESCALE>
__global__ void __launch_bounds__(256)
xp_gemm(const void* __restrict__ Av, const float* __restrict__ W,
        const float* __restrict__ bias, const float* __restrict__ esc,
        unsigned short* __restrict__ outp, int N)
{
    __shared__ unsigned short Asm[128][40];
    __shared__ unsigned short Bsm[8][64][8];
    __shared__ float esm[ESCALE ? K : 1];

    const int tid  = threadIdx.x;
    const int lane = tid & 63;
    const int wv   = tid >> 6;
    const int wm   = wv & 1;
    const int wn   = wv >> 1;
    const size_t m0 = (size_t)blockIdx.x * 128;
    const int n0   = blockIdx.y * 128;

    if constexpr (ESCALE){
        for (int i = tid; i < K; i += 256) esm[i] = esc[(size_t)blockIdx.x*K + i];
    }

    f32x4 acc[4][4];
    #pragma unroll
    for (int nt = 0; nt < 4; ++nt){
        float bv = bias[n0 + wn*64 + nt*16 + (lane & 15)];
        #pragma unroll
        for (int mt = 0; mt < 4; ++mt)
            acc[mt][nt] = (f32x4){bv, bv, bv, bv};
    }

    const int bn = tid & 127;
    const int bg = tid >> 7;

    for (int k0 = 0; k0 < K; k0 += 32){
        __syncthreads();
        if constexpr (!ABF16){
            const float* Ag = (const float*)Av;
            #pragma unroll
            for (int i = 0; i < 2; ++i){
                int g = tid + i*256;
                int r = g >> 2, c8 = g & 3;
                float4 d0 = *(const float4*)(Ag + (m0 + r)*K + k0 + c8*8);
                float4 d1 = *(const float4*)(Ag + (m0 + r)*K + k0 + c8*8 + 4);
                union { unsigned short s[8]; uint4 v; } u;
                u.s[0]=f2b(d0.x); u.s[1]=f2b(d0.y); u.s[2]=f2b(d0.z); u.s[3]=f2b(d0.w);
                u.s[4]=f2b(d1.x); u.s[5]=f2b(d1.y); u.s[6]=f2b(d1.z); u.s[7]=f2b(d1.w);
                *(uint4*)&Asm[r][c8*8] = u.v;
            }
        } else {
            const unsigned short* Ag = (const unsigned short*)Av;
            #pragma unroll
            for (int i = 0; i < 2; ++i){
                int g = tid + i*256;
                int r = g >> 2, c8 = g & 3;
                uint4 d = *(const uint4*)(Ag + (m0 + r)*K + k0 + c8*8);
                if constexpr (ESCALE){
                    unsigned short* s = (unsigned short*)&d;
                    #pragma unroll
                    for (int j = 0; j < 8; ++j)
                        s[j] = f2b(b2f(s[j]) * esm[k0 + c8*8 + j]);
                }
                *(uint4*)&Asm[r][c8*8] = d;
            }
        }
        {
            union { unsigned short s[8]; uint4 v; } u0, u1;
            #pragma unroll
            for (int q = 0; q < 8; ++q){
                u0.s[q] = f2b(W[(size_t)(k0 + bg*16 + q)*N + n0 + bn]);
                u1.s[q] = f2b(W[(size_t)(k0 + bg*16 + 8 + q)*N + n0 + bn]);
            }
            int nt = bn >> 4, lo = bn & 15;
            *(uint4*)&Bsm[nt][lo + 16*(2*bg)][0]   = u0.v;
            *(uint4*)&Bsm[nt][lo + 16*(2*bg+1)][0] = u1.v;
        }
        __syncthreads();

        bf16x8 af[4], bfr[4];
        #pragma unroll
        for (int mt = 0; mt < 4; ++mt)
            af[mt] = *(const bf16x8*)&Asm[wm*64 + mt*16 + (lane & 15)][(lane >> 4)*8];
        #pragma unroll
        for (int nt = 0; nt < 4; ++nt)
            bfr[nt] = *(const bf16x8*)&Bsm[wn*4 + nt][lane][0];
        #pragma unroll
        for (int mt = 0; mt < 4; ++mt)
            #pragma unroll
            for (int nt = 0; nt < 4; ++nt)
                acc[mt][nt] = __builtin_amdgcn_mfma_f32_16x16x32_bf16(af[mt], bfr[nt], acc[mt][nt], 0, 0, 0);
    }

    #pragma unroll
    for (int mt = 0; mt < 4; ++mt)
        #pragma unroll
        for (int nt = 0; nt < 4; ++nt)
            #pragma unroll
            for (int r = 0; r < 4; ++r){
                size_t row = m0 + wm*64 + mt*16 + (lane >> 4)*4 + r;
                int    col = n0 + wn*64 + nt*16 + (lane & 15);
                if constexpr (OUTMODE == 0){
                    outp[row*N + col] = f2b(acc[mt][nt][r]);
                } else if constexpr (OUTMODE == 1){
                    size_t off = ((size_t)((row >> 7)*8 + (col >> 5))*32 + (col & 31))*128 + (row & 127);
                    outp[off] = f2b(acc[mt][nt][r]);
                } else {
                    const int U = N/4;
                    outp[row*N + (col & (U-1))*4 + (col / U)] = f2b(acc[mt][nt][r]);
                }
            }
}

// ---------------- LSTM recurrence v8: round-4 structure (RB=4, z_lds, spread gate) + prepped bf16 R ----------------
// 256 blocks (128 x 2 dirs), 512 threads = 8 waves. Wave wv owns z cols [wv*Z/8, ...). rf = vector
// loads from prepped frag buffer (no per-step f2b). Gate math: 512 threads, 1 unit-row each (U=128)
// or 256 threads (U=64). c-state per gate thread in a single register.
template<int U, bool OUT_BF16>
__global__ void __launch_bounds__(512)
lstm_rec8(const unsigned short* __restrict__ xpf, const unsigned short* __restrict__ xpb,
          const unsigned short* __restrict__ Rff, const unsigned short* __restrict__ Rbf,
          const float* __restrict__ bng, const float* __restrict__ bnb,
          const float* __restrict__ bnm, const float* __restrict__ bnv,
          unsigned short* __restrict__ outv)
{
    constexpr int Z    = 4*U;
    constexpr int KT   = U/32;
    constexpr int NTW  = Z/128;     // n-tiles per wave (8 waves)
    constexpr int NT16 = Z/16;
    constexpr int HP   = U + 8;

    __shared__ unsigned short h_lds[16][HP];
    __shared__ float z_lds[4][Z];

    const int tid  = threadIdx.x;
    const int lane = tid & 63;
    const int wv   = tid >> 6;
    const int dir  = blockIdx.y;
    const int b0   = blockIdx.x * 4;
    const int ncol0 = wv * (Z/8);

    const unsigned short* xp = dir ? xpb : xpf;
    const unsigned short* Rp = dir ? Rbf : Rff;

    for (int i = tid; i < 16*HP; i += 512) ((unsigned short*)h_lds)[i] = 0;

    // prepped R fragments: one 16B vector load each, no conversion
    bf16x8 rf[KT][NTW];
    #pragma unroll
    for (int kt = 0; kt < KT; ++kt)
        #pragma unroll
        for (int nt = 0; nt < NTW; ++nt)
            rf[kt][nt] = *(const bf16x8*)(Rp + (((size_t)kt*NT16 + wv*NTW + nt)*64 + lane)*8);

    const int u_  = tid % U;
    const int r_  = tid / U;
    const bool gate = (tid < 4*U);
    float c_ = 0.f;
    float bns = 0.f, bnsh = 0.f;
    const int ch = dir*U + u_;
    if (gate){
        bns  = bng[ch] * rsqrtf(bnv[ch] + EPS);
        bnsh = bnb[ch] - bnm[ch]*bns;
    }
    const unsigned short* xbase = xp + (size_t)(b0 + (gate ? r_ : 0))*128*Z + u_*4;
    __syncthreads();

    ushort4 xq = {0,0,0,0};
    if (gate) xq = *(const ushort4*)(xbase + (size_t)(dir ? 127 : 0)*Z);

    for (int ts = 0; ts < 128; ++ts){
        const int t = dir ? 127 - ts : ts;
        ushort4 xn = xq;
        if (gate && ts < 127){
            int tn = dir ? t - 1 : t + 1;
            xn = *(const ushort4*)(xbase + (size_t)tn*Z);
        }
        bf16x8 af[KT];
        #pragma unroll
        for (int kt = 0; kt < KT; ++kt)
            af[kt] = *(const bf16x8*)&h_lds[lane & 15][kt*32 + (lane >> 4)*8];
        f32x4 acc[NTW];
        #pragma unroll
        for (int nt = 0; nt < NTW; ++nt) acc[nt] = (f32x4){0.f,0.f,0.f,0.f};
        #pragma unroll
        for (int kt = 0; kt < KT; ++kt)
            #pragma unroll
            for (int nt = 0; nt < NTW; ++nt)
                acc[nt] = __builtin_amdgcn_mfma_f32_16x16x32_bf16(af[kt], rf[kt][nt], acc[nt], 0, 0, 0);
        if ((lane >> 4) == 0){
            #pragma unroll
            for (int nt = 0; nt < NTW; ++nt)
                #pragma unroll
                for (int r = 0; r < 4; ++r)
                    z_lds[r][ncol0 + nt*16 + (lane & 15)] = acc[nt][r];
        }
        __syncthreads();
        if (gate){
            float z0 = z_lds[r_][u_      ] + b2f(xn.x*0 + xq.x);
            float z1 = z_lds[r_][u_ +  U ] + b2f(xq.y);
            float z2 = z_lds[r_][u_ + 2*U] + b2f(xq.z);
            float z3 = z_lds[r_][u_ + 3*U] + b2f(xq.w);
            float iv = sigm(z0), fv = sigm(z1), gv = tanhfast(z2), ov = sigm(z3);
            c_ = fv*c_ + iv*gv;
            float h = ov * tanhfast(c_);
            h_lds[r_][u_] = f2b(h);
            float hb = fmaf(h, bns, bnsh);
            size_t oidx = ((size_t)(b0 + r_)*128 + t)*(size_t)(2*U) + ch;
            if constexpr (OUT_BF16) outv[oidx] = f2b(hb);
            else                    ((float*)outv)[oidx] = hb;
        }
        __syncthreads();
        xq = xn;
    }
}

// ---------------- MFMA attention per (b, head) ----------------
__global__ void __launch_bounds__(256)
attn_kernel(const unsigned short* __restrict__ qb,
            const unsigned short* __restrict__ kb,
            const unsigned short* __restrict__ vb,
            float* __restrict__ msum)
{
    __shared__ unsigned short p_lds[128][136];
    __shared__ float red[4][2][16];

    const int b  = blockIdx.x, hd = blockIdx.y;
    const int tid = threadIdx.x, lane = tid & 63, wv = tid >> 6;
    const int m0 = wv * 32;
    const int l15 = lane & 15, lg = lane >> 4;

    bf16x8 aq[2];
    #pragma unroll
    for (int mt = 0; mt < 2; ++mt)
        aq[mt] = *(const bf16x8*)(qb + ((size_t)(b*128 + m0 + mt*16 + l15))*256 + hd*32 + lg*8);

    bf16x8 bk[8];
    #pragma unroll
    for (int nt = 0; nt < 8; ++nt)
        bk[nt] = *(const bf16x8*)(kb + ((size_t)(b*128 + nt*16 + l15))*256 + hd*32 + lg*8);

    f32x4 s[2][8];
    #pragma unroll
    for (int mt = 0; mt < 2; ++mt)
        #pragma unroll
        for (int nt = 0; nt < 8; ++nt) s[mt][nt] = (f32x4){0.f,0.f,0.f,0.f};
    #pragma unroll
    for (int mt = 0; mt < 2; ++mt)
        #pragma unroll
        for (int nt = 0; nt < 8; ++nt)
            s[mt][nt] = __builtin_amdgcn_mfma_f32_16x16x32_bf16(aq[mt], bk[nt], s[mt][nt], 0, 0, 0);

    const float scale = 0.17677669529663687f;
    #pragma unroll
    for (int mt = 0; mt < 2; ++mt)
        #pragma unroll
        for (int r = 0; r < 4; ++r){
            float mx = -1e30f;
            #pragma unroll
            for (int nt = 0; nt < 8; ++nt) mx = fmaxf(mx, s[mt][nt][r]);
            #pragma unroll
            for (int msk = 1; msk < 16; msk <<= 1) mx = fmaxf(mx, __shfl_xor(mx, msk, 64));
            float pv[8], sum = 0.f;
            #pragma unroll
            for (int nt = 0; nt < 8; ++nt){
                pv[nt] = __expf((s[mt][nt][r] - mx) * scale);
                sum += pv[nt];
            }
            #pragma unroll
            for (int msk = 1; msk < 16; msk <<= 1) sum += __shfl_xor(sum, msk, 64);
            float inv = 1.f / sum;
            int row = m0 + mt*16 + lg*4 + r;
            #pragma unroll
            for (int nt = 0; nt < 8; ++nt)
                p_lds[row][nt*16 + l15] = f2b(pv[nt] * inv);
        }
    __syncthreads();

    f32x4 o[2][2];
    #pragma unroll
    for (int mt = 0; mt < 2; ++mt)
        #pragma unroll
        for (int dn = 0; dn < 2; ++dn) o[mt][dn] = (f32x4){0.f,0.f,0.f,0.f};
    bf16x8 bv[4][2];
    #pragma unroll
    for (int kt = 0; kt < 4; ++kt)
        #pragma unroll
        for (int dn = 0; dn < 2; ++dn)
            bv[kt][dn] = *(const bf16x8*)(vb + ((size_t)(b*8 + hd)*32 + dn*16 + l15)*128 + kt*32 + lg*8);
    #pragma unroll
    for (int mt = 0; mt < 2; ++mt)
        #pragma unroll
        for (int kt = 0; kt < 4; ++kt){
            bf16x8 ap = *(const bf16x8*)&p_lds[m0 + mt*16 + l15][kt*32 + lg*8];
            #pragma unroll
            for (int dn = 0; dn < 2; ++dn)
                o[mt][dn] = __builtin_amdgcn_mfma_f32_16x16x32_bf16(ap, bv[kt][dn], o[mt][dn], 0, 0, 0);
        }

    float sm[2];
    #pragma unroll
    for (int dn = 0; dn < 2; ++dn){
        float a = 0.f;
        #pragma unroll
        for (int mt = 0; mt < 2; ++mt)
            #pragma unroll
            for (int r = 0; r < 4; ++r) a += o[mt][dn][r];
        a += __shfl_xor(a, 16, 64);
        a += __shfl_xor(a, 32, 64);
        sm[dn] = a;
    }
    if (lg == 0){
        red[wv][0][l15] = sm[0];
        red[wv][1][l15] = sm[1];
    }
    __syncthreads();
    if (tid < 32){
        int dn = tid >> 4, n = tid & 15;
        float tot = red[0][dn][n] + red[1][dn][n] + red[2][dn][n] + red[3][dn][n];
        msum[(size_t)b*256 + hd*32 + dn*16 + n] = tot * (1.f/128.f);
    }
}

// ---------------- head ----------------
__global__ void __launch_bounds__(256)
head_kernel(const float* __restrict__ msum,
            const float* __restrict__ wo, const float* __restrict__ bo,
            const float* __restrict__ d1w, const float* __restrict__ d1b,
            const float* __restrict__ g1, const float* __restrict__ b1,
            const float* __restrict__ m1, const float* __restrict__ v1,
            const float* __restrict__ d2w, const float* __restrict__ d2b,
            const float* __restrict__ g2, const float* __restrict__ b2,
            const float* __restrict__ m2, const float* __restrict__ v2,
            const float* __restrict__ d3w, const float* __restrict__ d3b,
            float* __restrict__ outp)
{
    int b = blockIdx.x, j = threadIdx.x;
    __shared__ float s1[256];
    __shared__ float s2[256];
    const float* mr = msum + (size_t)b*256;
    float acc = bo[j];
    #pragma unroll 4
    for (int i = 0; i < 256; ++i) acc = fmaf(mr[i], wo[i*256 + j], acc);
    s1[j] = acc;
    __syncthreads();
    float a1 = d1b[j];
    #pragma unroll 4
    for (int i = 0; i < 256; ++i) a1 = fmaf(s1[i], d1w[i*256 + j], a1);
    a1 = fmaxf(a1, 0.f);
    float sc1 = g1[j] * rsqrtf(v1[j] + EPS);
    a1 = a1 * sc1 + (b1[j] - m1[j] * sc1);
    s2[j] = a1;
    __syncthreads();
    if (j < 128){
        float a2 = d2b[j];
        #pragma unroll 4
        for (int i = 0; i < 256; ++i) a2 = fmaf(s2[i], d2w[i*128 + j], a2);
        a2 = fmaxf(a2, 0.f);
        float sc2 = g2[j] * rsqrtf(v2[j] + EPS);
        a2 = a2 * sc2 + (b2[j] - m2[j] * sc2);
        s1[j] = a2;
    }
    __syncthreads();
    if (j == 0){
        float a3 = d3b[0];
        for (int i = 0; i < 128; ++i) a3 = fmaf(s1[i], d3w[i], a3);
        outp[b] = sigm(a3);
    }
}

extern "C" void kernel_launch(void* const* d_in, const int* in_sizes, int n_in,
                              void* d_out, int out_size, void* d_ws, size_t ws_size,
                              hipStream_t stream)
{
    #define F(i) ((const float*)d_in[i])
    const float* x       = F(0);
    const float* conv5_w = F(1);
    const float* conv7_w = F(2);
    const float* conv9_w = F(3);
    const float* fuse_w  = F(4);
    const float* se_w1   = F(5);
    const float* se_w2   = F(6);
    const float* l1f_k   = F(7);
    const float* l1f_r   = F(8);
    const float* l1b_k   = F(9);
    const float* l1b_r   = F(10);
    const float* l2f_k   = F(11);
    const float* l2f_r   = F(12);
    const float* l2b_k   = F(13);
    const float* l2b_r   = F(14);
    const float* wq      = F(15);
    const float* wk      = F(16);
    const float* wv      = F(17);
    const float* wo      = F(18);
    const float* d1_w    = F(19);
    const float* d2_w    = F(20);
    const float* d3_w    = F(21);
    const float* conv5_b = F(22);
    const float* conv7_b = F(23);
    const float* conv9_b = F(24);
    const float* fuse_b  = F(25);
    const float* se_b1   = F(26);
    const float* se_b2   = F(27);
    const float* l1f_b   = F(28);
    const float* l1b_b   = F(29);
    const float* l2f_b   = F(30);
    const float* l2b_b   = F(31);
    const float* bq      = F(32);
    const float* bk      = F(33);
    const float* bv      = F(34);
    const float* bo      = F(35);
    const float* d1_b    = F(36);
    const float* d2_b    = F(37);
    const float* d3_b    = F(38);
    const float* bn5_g = F(39), *bn5_b = F(40), *bn5_m = F(41), *bn5_v = F(42);
    const float* bn7_g = F(43), *bn7_b = F(44), *bn7_m = F(45), *bn7_v = F(46);
    const float* bn9_g = F(47), *bn9_b = F(48), *bn9_m = F(49), *bn9_v = F(50);
    const float* bnl1_g = F(51), *bnl1_b = F(52), *bnl1_m = F(53), *bnl1_v = F(54);
    const float* bnl2_g = F(55), *bnl2_b = F(56), *bnl2_m = F(57), *bnl2_v = F(58);
    const float* bnd1_g = F(59), *bnd1_b = F(60), *bnd1_m = F(61), *bnd1_v = F(62);
    const float* bnd2_g = F(63), *bnd2_b = F(64), *bnd2_m = F(65), *bnd2_v = F(66);
    #undef F

    float* ws = (float*)d_ws;
    // round-5 proven layout + R-prepped buffers in the always-free hole [27690560, 29360128)
    float* concat = ws;
    unsigned short* fusedbf = (unsigned short*)(ws + 12582912);
    float* e      = ws + 16777216;
    unsigned short* xbf   = (unsigned short*)(ws + 20971520);
    unsigned short* wfrag = (unsigned short*)(ws + 27607040);
    float* biascat = ws + 27689984;
    float* cscale  = ws + 27690176;
    float* cshift  = ws + 27690368;
    unsigned short* l1frb = (unsigned short*)(ws + 27690560);  // 65536 shorts
    unsigned short* l1brb = (unsigned short*)(ws + 27723328);
    unsigned short* l2frb = (unsigned short*)(ws + 27756096);  // 16384 shorts
    unsigned short* l2brb = (unsigned short*)(ws + 27764288);  // ends 27772480
    unsigned short* xp1f  = (unsigned short*)(ws);
    unsigned short* xp1b  = (unsigned short*)(ws + 20971520);
    unsigned short* l1out = (unsigned short*)(ws + 29360128);
    unsigned short* xp2f  = (unsigned short*)(ws);
    unsigned short* xp2b  = (unsigned short*)(ws + 4194304);
    unsigned short* l2out = (unsigned short*)(ws + 8388608);
    unsigned short* qbuf  = (unsigned short*)(ws + 12582912);
    unsigned short* kbuf  = (unsigned short*)(ws);
    unsigned short* vbuf  = (unsigned short*)(ws + 20971520);
    float* msum   = ws + 29360128;
    float* outp   = (float*)d_out;

    // conv prep + fused conv GEMM
    prep_x<<<dim3(512), dim3(256), 0, stream>>>(x, xbf);
    prep_w<<<dim3(81), dim3(256), 0, stream>>>(conv5_w, conv7_w, conv9_w, wfrag);
    prep_ss<<<dim3(1), dim3(192), 0, stream>>>(
        conv5_b, conv7_b, conv9_b,
        bn5_g, bn5_b, bn5_m, bn5_v,
        bn7_g, bn7_b, bn7_m, bn7_v,
        bn9_g, bn9_b, bn9_m, bn9_v,
        biascat, cscale, cshift);
    prep_wb<<<dim3(32), dim3(256), 0, stream>>>(l1f_r, l1frb, 128, 512);
    prep_wb<<<dim3(32), dim3(256), 0, stream>>>(l1b_r, l1brb, 128, 512);
    prep_wb<<<dim3(8),  dim3(256), 0, stream>>>(l2f_r, l2frb, 64, 256);
    prep_wb<<<dim3(8),  dim3(256), 0, stream>>>(l2b_r, l2brb, 64, 256);
    conv_mfma<<<dim3(512,4), dim3(256), 0, stream>>>(
        xbf, wfrag, biascat, cscale, cshift, concat);

    // 1x1 fuse as MFMA GEMM (bf16 out), SE excitation only
    xp_gemm<192,false,0,false><<<dim3(512,1), dim3(256), 0, stream>>>(
        concat, fuse_w, fuse_b, nullptr, fusedbf, 128);
    se_mean<<<dim3(512), dim3(128), 0, stream>>>(fusedbf, se_w1, se_b1, se_w2, se_b2, e);

    // BiLSTM 1 (xp gate-interleaved, SE scale applied in staging)
    xp_gemm<128,true,2,true><<<dim3(512,4), dim3(256), 0, stream>>>(
        fusedbf, l1f_k, l1f_b, e, xp1f, 512);
    xp_gemm<128,true,2,true><<<dim3(512,4), dim3(256), 0, stream>>>(
        fusedbf, l1b_k, l1b_b, e, xp1b, 512);
    lstm_rec8<128,true><<<dim3(128,2), dim3(512), 0, stream>>>(
        xp1f, xp1b, l1frb, l1brb, bnl1_g, bnl1_b, bnl1_m, bnl1_v, l1out);

    // BiLSTM 2
    xp_gemm<256,true,2,false><<<dim3(512,2), dim3(256), 0, stream>>>(
        l1out, l2f_k, l2f_b, nullptr, xp2f, 256);
    xp_gemm<256,true,2,false><<<dim3(512,2), dim3(256), 0, stream>>>(
        l1out, l2b_k, l2b_b, nullptr, xp2b, 256);
    lstm_rec8<64,true><<<dim3(128,2), dim3(512), 0, stream>>>(
        xp2f, xp2b, l2frb, l2brb, bnl2_g, bnl2_b, bnl2_m, bnl2_v, l2out);

    // QKV projections; V per-head-transposed
    xp_gemm<128,true,0,false><<<dim3(512,2), dim3(256), 0, stream>>>(
        l2out, wq, bq, nullptr, qbuf, 256);
    xp_gemm<128,true,0,false><<<dim3(512,2), dim3(256), 0, stream>>>(
        l2out, wk, bk, nullptr, kbuf, 256);
    xp_gemm<128,true,1,false><<<dim3(512,2), dim3(256), 0, stream>>>(
        l2out, wv, bv, nullptr, vbuf, 256);

    // MFMA attention + T-mean
    attn_kernel<<<dim3(512,8), dim3(256), 0, stream>>>(qbuf, kbuf, vbuf, msum);

    // wo + dense head
    head_kernel<<<dim3(512), dim3(256), 0, stream>>>(
        msum, wo, bo,
        d1_w, d1_b, bnd1_g, bnd1_b, bnd1_m, bnd1_v,
        d2_w, d2_b, bnd2_g, bnd2_b, bnd2_m, bnd2_v,
        d3_w, d3_b, outp);

    (void)in_sizes; (void)n_in; (void)out_size; (void)ws_size;
}